// Round 2
// 745.360 us; speedup vs baseline: 1.0473x; 1.0473x over previous
//
#include <hip/hip_runtime.h>
#include <hip/hip_bf16.h>

#define NU 200000
#define NI 100000
#define NN 300000
#define NE 1500000
#define BD 384

#define SCAN1_BLOCKS 293   // ceil(NN / 1024)
#define NBINS 293          // ceil(NN / 1024), 1024 rows per bin
#define CH 4096            // edges per binscat block (16 per thread)
#define P2CAP 6144         // pass-2 LDS staging capacity (avg bin = 5120)

typedef __attribute__((ext_vector_type(8))) short short8;
typedef __attribute__((ext_vector_type(4))) float floatx4;

// ---------------------------------------------------------------------------
__device__ __forceinline__ void fma4(float4& a, float s, const float4& w) {
    a.x = fmaf(s, w.x, a.x);
    a.y = fmaf(s, w.y, a.y);
    a.z = fmaf(s, w.z, a.z);
    a.w = fmaf(s, w.w, a.w);
}

// pack 8 fp32 -> 8 bf16 (RNE)
__device__ __forceinline__ short8 cvt8(const float4 a, const float4 b) {
    union { short8 v; __hip_bfloat16 e[8]; } u;
    u.e[0] = __float2bfloat16(a.x); u.e[1] = __float2bfloat16(a.y);
    u.e[2] = __float2bfloat16(a.z); u.e[3] = __float2bfloat16(a.w);
    u.e[4] = __float2bfloat16(b.x); u.e[5] = __float2bfloat16(b.y);
    u.e[6] = __float2bfloat16(b.z); u.e[7] = __float2bfloat16(b.w);
    return u.v;
}

// ---------------------------------------------------------------------------
// user rows: A[u] = user_emb + gender_emb[g] + age_emb[a]   (out deferred)
// ---------------------------------------------------------------------------
__global__ __launch_bounds__(256) void user_init_k(
    const float4* __restrict__ user_emb,
    const float4* __restrict__ gender_emb,
    const float4* __restrict__ age_emb,
    const int* __restrict__ ug,
    const int* __restrict__ ua,
    float4* __restrict__ A)
{
    int i = blockIdx.x * 256 + threadIdx.x;   // [0, NU*16)
    int u = i >> 4, q = i & 15;
    float4 e = user_emb[i];
    float4 g = gender_emb[ug[u] * 16 + q];
    float4 a = age_emb[ua[u] * 16 + q];
    e.x += g.x + a.x; e.y += g.y + a.y; e.z += g.z + a.z; e.w += g.w + a.w;
    A[i] = e;
}

// ---------------------------------------------------------------------------
// item rows via bf16 MFMA, no LDS:
//   A[NU+i] = item_emb[i] + cat_emb[icat[i]] + bert[i] @ W^T
// ---------------------------------------------------------------------------
__global__ __launch_bounds__(256) void item_init_k(
    const float* __restrict__ bert,        // [NI][384]
    const float* __restrict__ W,           // [64][384]
    const float* __restrict__ item_emb,    // [NI][64]
    const float* __restrict__ cat_emb,     // [11][64]
    const int* __restrict__ icat,
    float* __restrict__ A)                 // [NN][64]
{
    const int lid = threadIdx.x & 63;
    const int wv  = threadIdx.x >> 6;
    const int i0  = (blockIdx.x * 4 + wv) * 16;
    if (i0 >= NI) return;
    const int m16 = lid & 15;
    const int q   = lid >> 4;

    const float* ab = bert + (size_t)(i0 + m16) * BD + q * 8;
    const float* b0 = W + (size_t)(m16 +  0) * BD + q * 8;
    const float* b1 = W + (size_t)(m16 + 16) * BD + q * 8;
    const float* b2 = W + (size_t)(m16 + 32) * BD + q * 8;
    const float* b3 = W + (size_t)(m16 + 48) * BD + q * 8;

    floatx4 cf[4];
    cf[0] = (floatx4){0.f, 0.f, 0.f, 0.f};
    cf[1] = cf[0]; cf[2] = cf[0]; cf[3] = cf[0];

    for (int k0 = 0; k0 < BD; k0 += 32) {
        short8 af = cvt8(*(const float4*)(ab + k0), *(const float4*)(ab + k0 + 4));
        short8 f0 = cvt8(*(const float4*)(b0 + k0), *(const float4*)(b0 + k0 + 4));
        short8 f1 = cvt8(*(const float4*)(b1 + k0), *(const float4*)(b1 + k0 + 4));
        short8 f2 = cvt8(*(const float4*)(b2 + k0), *(const float4*)(b2 + k0 + 4));
        short8 f3 = cvt8(*(const float4*)(b3 + k0), *(const float4*)(b3 + k0 + 4));
        cf[0] = __builtin_amdgcn_mfma_f32_16x16x32_bf16(af, f0, cf[0], 0, 0, 0);
        cf[1] = __builtin_amdgcn_mfma_f32_16x16x32_bf16(af, f1, cf[1], 0, 0, 0);
        cf[2] = __builtin_amdgcn_mfma_f32_16x16x32_bf16(af, f2, cf[2], 0, 0, 0);
        cf[3] = __builtin_amdgcn_mfma_f32_16x16x32_bf16(af, f3, cf[3], 0, 0, 0);
    }

    #pragma unroll
    for (int r = 0; r < 4; ++r) {
        const int item = i0 + q * 4 + r;
        const int cat  = icat[item];
        const size_t eb = (size_t)item * 64;
        const size_t abn = (size_t)(NU + item) * 64;
        #pragma unroll
        for (int td = 0; td < 4; ++td) {
            const int d = td * 16 + m16;
            A[abn + d] = cf[td][r] + item_emb[eb + d] + cat_emb[cat * 64 + d];
        }
    }
}

// ---------------------------------------------------------------------------
// CSR build: histogram -> 2-level exclusive scan -> binned 2-pass scatter
// ---------------------------------------------------------------------------
__global__ __launch_bounds__(256) void hist_k(
    const int* __restrict__ row, int* __restrict__ counts)
{
    int e = blockIdx.x * 256 + threadIdx.x;
    if (e < NE) atomicAdd(&counts[row[e]], 1);
}

__global__ __launch_bounds__(256) void scan1_k(
    const int* __restrict__ counts, int* __restrict__ offs,
    int* __restrict__ blksum)
{
    __shared__ int s[256];
    int t = threadIdx.x;
    int base = blockIdx.x * 1024 + t * 4;
    int c0 = 0, c1 = 0, c2 = 0, c3 = 0;
    if (base + 3 < NN) {
        int4 c = *(const int4*)&counts[base];
        c0 = c.x; c1 = c.y; c2 = c.z; c3 = c.w;
    } else {
        if (base + 0 < NN) c0 = counts[base + 0];
        if (base + 1 < NN) c1 = counts[base + 1];
        if (base + 2 < NN) c2 = counts[base + 2];
    }
    int tsum = c0 + c1 + c2 + c3;
    s[t] = tsum;
    __syncthreads();
    for (int d = 1; d < 256; d <<= 1) {
        int v = (t >= d) ? s[t - d] : 0;
        __syncthreads();
        s[t] += v;
        __syncthreads();
    }
    if (t == 255) blksum[blockIdx.x] = s[255];
    int e0 = s[t] - tsum, e1 = e0 + c0, e2 = e1 + c1, e3 = e2 + c2;
    if (base + 0 < NN) offs[base + 0] = e0;
    if (base + 1 < NN) offs[base + 1] = e1;
    if (base + 2 < NN) offs[base + 2] = e2;
    if (base + 3 < NN) offs[base + 3] = e3;
}

__global__ __launch_bounds__(512) void scan2_k(int* __restrict__ blksum)
{
    __shared__ int s[512];
    int t = threadIdx.x;
    int v = (t < SCAN1_BLOCKS) ? blksum[t] : 0;
    s[t] = v;
    __syncthreads();
    for (int d = 1; d < 512; d <<= 1) {
        int x = (t >= d) ? s[t - d] : 0;
        __syncthreads();
        s[t] += x;
        __syncthreads();
    }
    if (t < SCAN1_BLOCKS) blksum[t] = s[t] - v;
}

__global__ __launch_bounds__(256) void addoff_k(
    int* __restrict__ offs, const int* __restrict__ blkoff,
    int* __restrict__ cursor,
    int* __restrict__ binstart, int* __restrict__ bincur)
{
    int i = blockIdx.x * 256 + threadIdx.x;
    if (i < NN) {
        int o = offs[i] + blkoff[i >> 10];
        offs[i] = o;
        cursor[i] = o;
        if ((i & 1023) == 0) {          // bin boundary: rows [b*1024,(b+1)*1024)
            binstart[i >> 10] = o;
            bincur[i >> 10] = o;
        }
    }
}

// ---------------------------------------------------------------------------
// Pass 1: block-level counting sort of 4096-edge chunks into 1024-row bins.
// Output tmp arrays are written as contiguous per-bin runs (dense, coalesced).
// Bin regions in tmp coincide exactly with final CSR bin ranges.
// grid: ceil(NE/CH) = 367
// ---------------------------------------------------------------------------
__global__ __launch_bounds__(256) void binscat_k(
    const int* __restrict__ row, const int* __restrict__ col,
    const float* __restrict__ val,
    int* __restrict__ bincur,
    int2* __restrict__ tcv, int* __restrict__ trow)
{
    __shared__ int lhist[512];   // padded bin histogram / counts
    __shared__ int lexcl[512];   // local exclusive offsets
    __shared__ int lbase[512];   // global base per bin for this block
    __shared__ int s[256];
    __shared__ int2 scv[CH];     // bin-sorted (col,val)
    __shared__ int  srow[CH];    // bin-sorted row

    int t = threadIdx.x;
    int e0 = blockIdx.x * CH;
    int n = NE - e0; if (n > CH) n = CH;

    lhist[t] = 0; lhist[t + 256] = 0;
    __syncthreads();

    int r[16]; int2 cv[16]; int rk[16];
    #pragma unroll
    for (int i = 0; i < 16; ++i) {
        int idx = e0 + i * 256 + t;
        if (idx < NE) {
            r[i] = row[idx];
            cv[i].x = col[idx];
            cv[i].y = __float_as_int(val[idx]);
            rk[i] = atomicAdd(&lhist[r[i] >> 10], 1);   // rank within bin
        }
    }
    __syncthreads();

    // exclusive scan over 512 padded bins, 2 per thread
    int c0 = lhist[2 * t], c1 = lhist[2 * t + 1];
    int tsum = c0 + c1;
    s[t] = tsum;
    __syncthreads();
    for (int d = 1; d < 256; d <<= 1) {
        int v = (t >= d) ? s[t - d] : 0;
        __syncthreads();
        s[t] += v;
        __syncthreads();
    }
    int ex = s[t] - tsum;
    lexcl[2 * t] = ex; lexcl[2 * t + 1] = ex + c0;
    // one global allocation per non-empty bin
    if (2 * t < NBINS && c0 > 0)     lbase[2 * t]     = atomicAdd(&bincur[2 * t], c0);
    if (2 * t + 1 < NBINS && c1 > 0) lbase[2 * t + 1] = atomicAdd(&bincur[2 * t + 1], c1);
    __syncthreads();

    // scatter into LDS at bin-sorted positions
    #pragma unroll
    for (int i = 0; i < 16; ++i) {
        int idx = e0 + i * 256 + t;
        if (idx < NE) {
            int b = r[i] >> 10;
            int p = lexcl[b] + rk[i];
            scv[p] = cv[i];
            srow[p] = r[i];
        }
    }
    __syncthreads();

    // write out: consecutive p -> consecutive global addresses per bin run
    for (int p = t; p < n; p += 256) {
        int rr = srow[p];
        int b = rr >> 10;
        int g = lbase[b] + (p - lexcl[b]);
        tcv[g] = scv[p];
        trow[g] = rr;
    }
}

// ---------------------------------------------------------------------------
// Pass 2: one block per bin. Sequential read of bin's tmp edges, per-row
// cursor atomics (cursor becomes `ends` for spmm), LDS staging so the final
// edges write is a fully coalesced stream over the bin's CSR range.
// grid: NBINS = 293
// ---------------------------------------------------------------------------
__global__ __launch_bounds__(256) void scatter2_k(
    const int2* __restrict__ tcv, const int* __restrict__ trow,
    const int* __restrict__ binstart,
    int* __restrict__ cursor, int2* __restrict__ edges)
{
    __shared__ int2 scv[P2CAP];
    int b = blockIdx.x;
    int s = binstart[b];
    int e = (b + 1 < NBINS) ? binstart[b + 1] : NE;
    int cnt = e - s;

    if (cnt <= P2CAP) {
        for (int p = s + threadIdx.x; p < e; p += 256) {
            int rr = trow[p];
            int pos = atomicAdd(&cursor[rr], 1);
            scv[pos - s] = tcv[p];
        }
        __syncthreads();
        for (int p = threadIdx.x; p < cnt; p += 256)
            edges[s + p] = scv[p];
    } else {
        // safety fallback (never expected with uniform rows)
        for (int p = s + threadIdx.x; p < e; p += 256) {
            int rr = trow[p];
            int pos = atomicAdd(&cursor[rr], 1);
            edges[pos] = tcv[p];
        }
    }
}

// ---------------------------------------------------------------------------
// CSR gather SpMM, 4-way unrolled for memory-level parallelism.
// ---------------------------------------------------------------------------
__global__ __launch_bounds__(256) void spmm_csr_k(
    const float4* __restrict__ x,
    float4* __restrict__ y,
    float4* __restrict__ out,
    const int* __restrict__ offs,
    const int* __restrict__ ends,
    const int2* __restrict__ edges,
    int mode)
{
    int t = threadIdx.x;
    int r = blockIdx.x * 16 + (t >> 4);
    int q = t & 15;
    int s = offs[r], e = ends[r];
    float4 acc = make_float4(0.f, 0.f, 0.f, 0.f);
    int k = s;
    for (; k + 4 <= e; k += 4) {
        int2 c0 = edges[k + 0];
        int2 c1 = edges[k + 1];
        int2 c2 = edges[k + 2];
        int2 c3 = edges[k + 3];
        float4 x0 = x[c0.x * 16 + q];
        float4 x1 = x[c1.x * 16 + q];
        float4 x2 = x[c2.x * 16 + q];
        float4 x3 = x[c3.x * 16 + q];
        fma4(acc, __int_as_float(c0.y), x0);
        fma4(acc, __int_as_float(c1.y), x1);
        fma4(acc, __int_as_float(c2.y), x2);
        fma4(acc, __int_as_float(c3.y), x3);
    }
    for (; k < e; ++k) {
        int2 cv = edges[k];
        fma4(acc, __int_as_float(cv.y), x[cv.x * 16 + q]);
    }
    int oi = r * 16 + q;
    if (mode != 3) y[oi] = acc;
    float4 o;
    if (mode == 1) {
        float4 xr = x[oi];
        o = make_float4(0.25f * (xr.x + acc.x), 0.25f * (xr.y + acc.y),
                        0.25f * (xr.z + acc.z), 0.25f * (xr.w + acc.w));
    } else {
        o = out[oi];
        o.x = fmaf(0.25f, acc.x, o.x);
        o.y = fmaf(0.25f, acc.y, o.y);
        o.z = fmaf(0.25f, acc.z, o.z);
        o.w = fmaf(0.25f, acc.w, o.w);
    }
    out[oi] = o;
}

// ---------------------------------------------------------------------------
extern "C" void kernel_launch(void* const* d_in, const int* in_sizes, int n_in,
                              void* d_out, int out_size, void* d_ws, size_t ws_size,
                              hipStream_t stream)
{
    const float* user_emb    = (const float*)d_in[0];
    const float* item_emb    = (const float*)d_in[1];
    const float* gender_emb  = (const float*)d_in[2];
    const float* age_emb     = (const float*)d_in[3];
    const float* cat_emb     = (const float*)d_in[4];
    const float* bert_w      = (const float*)d_in[5];
    const float* item_bert   = (const float*)d_in[6];
    const float* adj_val     = (const float*)d_in[7];
    const int*   user_gender = (const int*)d_in[8];
    const int*   user_age    = (const int*)d_in[9];
    const int*   item_cat    = (const int*)d_in[10];
    const int*   adj_row     = (const int*)d_in[11];
    const int*   adj_col     = (const int*)d_in[12];

    float* out = (float*)d_out;

    // workspace layout (all 16B aligned)
    float* A       = (float*)d_ws;                 // [NN*64]
    float* B       = A + (size_t)NN * 64;          // [NN*64]
    int2*  edges   = (int2*)(B + (size_t)NN * 64); // [NE]
    int*   offs    = (int*)(edges + NE);           // [NN] (also counts)
    int*   cursor  = offs + NN;                    // [NN]
    int*   blksum  = cursor + NN;                  // [512]
    int*   binstart= blksum + 512;                 // [512]
    int*   bincur  = binstart + 512;               // [512]

    // tmp binned edges alias into B (B is dead until spmm layer 1)
    int2* tcv  = (int2*)B;                         // [NE] 12 MB
    int*  trow = (int*)(tcv + NE);                 // [NE]  6 MB

    // --- CSR build ---
    hipMemsetAsync(offs, 0, (size_t)NN * sizeof(int), stream);
    hist_k<<<5860, 256, 0, stream>>>(adj_row, offs);
    scan1_k<<<SCAN1_BLOCKS, 256, 0, stream>>>(offs, offs, blksum);
    scan2_k<<<1, 512, 0, stream>>>(blksum);
    addoff_k<<<1172, 256, 0, stream>>>(offs, blksum, cursor, binstart, bincur);
    binscat_k<<<367, 256, 0, stream>>>(adj_row, adj_col, adj_val, bincur, tcv, trow);
    scatter2_k<<<NBINS, 256, 0, stream>>>(tcv, trow, binstart, cursor, edges);

    // --- layer-0 features into A (out contribution deferred to layer 1) ---
    user_init_k<<<12500, 256, 0, stream>>>(
        (const float4*)user_emb, (const float4*)gender_emb, (const float4*)age_emb,
        user_gender, user_age, (float4*)A);
    item_init_k<<<1563, 256, 0, stream>>>(
        item_bert, bert_w, item_emb, cat_emb, item_cat, A);

    // --- 3 propagation layers ---
    spmm_csr_k<<<18750, 256, 0, stream>>>(
        (const float4*)A, (float4*)B, (float4*)out, offs, cursor, edges, 1);
    spmm_csr_k<<<18750, 256, 0, stream>>>(
        (const float4*)B, (float4*)A, (float4*)out, offs, cursor, edges, 2);
    spmm_csr_k<<<18750, 256, 0, stream>>>(
        (const float4*)A, (float4*)B, (float4*)out, offs, cursor, edges, 3);
}

// Round 3
// 715.676 us; speedup vs baseline: 1.0907x; 1.0415x over previous
//
#include <hip/hip_runtime.h>
#include <hip/hip_bf16.h>

#define NU 200000
#define NI 100000
#define NN 300000
#define NE 1500000
#define BD 384

#define SCAN1_BLOCKS 293   // ceil(NN / 1024)
#define NBINS 293          // ceil(NN / 1024), 1024 rows per bin
#define CH 4096            // edges per binscat block (16 per thread)
#define P2CAP 6144         // pass-2 LDS staging capacity (avg bin = 5120)

typedef __attribute__((ext_vector_type(8))) short short8;
typedef __attribute__((ext_vector_type(4))) float floatx4;

// ---------------------------------------------------------------------------
__device__ __forceinline__ void fma4(float4& a, float s, const float4& w) {
    a.x = fmaf(s, w.x, a.x);
    a.y = fmaf(s, w.y, a.y);
    a.z = fmaf(s, w.z, a.z);
    a.w = fmaf(s, w.w, a.w);
}

// pack 8 fp32 -> 8 bf16 (RNE)
__device__ __forceinline__ short8 cvt8(const float4 a, const float4 b) {
    union { short8 v; __hip_bfloat16 e[8]; } u;
    u.e[0] = __float2bfloat16(a.x); u.e[1] = __float2bfloat16(a.y);
    u.e[2] = __float2bfloat16(a.z); u.e[3] = __float2bfloat16(a.w);
    u.e[4] = __float2bfloat16(b.x); u.e[5] = __float2bfloat16(b.y);
    u.e[6] = __float2bfloat16(b.z); u.e[7] = __float2bfloat16(b.w);
    return u.v;
}

// ---------------------------------------------------------------------------
// user rows: A[u] = user_emb + gender_emb[g] + age_emb[a]   (out deferred)
// ---------------------------------------------------------------------------
__global__ __launch_bounds__(256) void user_init_k(
    const float4* __restrict__ user_emb,
    const float4* __restrict__ gender_emb,
    const float4* __restrict__ age_emb,
    const int* __restrict__ ug,
    const int* __restrict__ ua,
    float4* __restrict__ A)
{
    int i = blockIdx.x * 256 + threadIdx.x;   // [0, NU*16)
    int u = i >> 4, q = i & 15;
    float4 e = user_emb[i];
    float4 g = gender_emb[ug[u] * 16 + q];
    float4 a = age_emb[ua[u] * 16 + q];
    e.x += g.x + a.x; e.y += g.y + a.y; e.z += g.z + a.z; e.w += g.w + a.w;
    A[i] = e;
}

// ---------------------------------------------------------------------------
// W fp32 [64][384] -> bf16 in MFMA B-fragment order:
//   Wb[(kt*4 + nt)*64 + lid] = short8{ W[nt*16 + m16][kt*32 + q*8 .. +7] }
//   where lid = q*16 + m16.  3072 entries of 16 B = 48 KB.
// ---------------------------------------------------------------------------
__global__ __launch_bounds__(256) void wconv_k(
    const float* __restrict__ W, short8* __restrict__ Wb)
{
    int t = blockIdx.x * 256 + threadIdx.x;   // entry index
    if (t >= 3072) return;
    int lid = t & 63, nt = (t >> 6) & 3, kt = t >> 8;
    int m16 = lid & 15, q = lid >> 4;
    const float* src = W + (size_t)(nt * 16 + m16) * BD + kt * 32 + q * 8;
    Wb[t] = cvt8(*(const float4*)src, *(const float4*)(src + 4));
}

// ---------------------------------------------------------------------------
// item rows via bf16 MFMA:
//   A[NU+i] = item_emb[i] + cat_emb[icat[i]] + bert[i] @ W^T
// B-frags come pre-converted + fragment-ordered from Wb (4 coalesced 16B/lane
// loads per K-step, L1/L2-resident). Only bert needs cvt (1 cvt8/K-step).
// Explicit depth-1 prefetch pipeline, fully unrolled (12 K-steps).
// ---------------------------------------------------------------------------
__global__ __launch_bounds__(256) void item_init_k(
    const float* __restrict__ bert,        // [NI][384]
    const short8* __restrict__ Wb,         // [3072] frag-ordered bf16 W
    const float* __restrict__ item_emb,    // [NI][64]
    const float* __restrict__ cat_emb,     // [11][64]
    const int* __restrict__ icat,
    float* __restrict__ A)                 // [NN][64]
{
    const int lid = threadIdx.x & 63;
    const int wv  = threadIdx.x >> 6;
    const int i0  = (blockIdx.x * 4 + wv) * 16;
    if (i0 >= NI) return;
    const int m16 = lid & 15;
    const int q   = lid >> 4;

    const float*  ab = bert + (size_t)(i0 + m16) * BD + q * 8;
    const short8* wb = Wb + lid;

    floatx4 cf[4];
    cf[0] = (floatx4){0.f, 0.f, 0.f, 0.f};
    cf[1] = cf[0]; cf[2] = cf[0]; cf[3] = cf[0];

    // prologue: K-step 0 in flight
    float4 a0 = *(const float4*)(ab + 0);
    float4 a1 = *(const float4*)(ab + 4);
    short8 b0 = wb[0 * 64];
    short8 b1 = wb[1 * 64];
    short8 b2 = wb[2 * 64];
    short8 b3 = wb[3 * 64];

    #pragma unroll
    for (int kt = 0; kt < 11; ++kt) {
        float4 na0 = *(const float4*)(ab + (kt + 1) * 32 + 0);
        float4 na1 = *(const float4*)(ab + (kt + 1) * 32 + 4);
        short8 nb0 = wb[((kt + 1) * 4 + 0) * 64];
        short8 nb1 = wb[((kt + 1) * 4 + 1) * 64];
        short8 nb2 = wb[((kt + 1) * 4 + 2) * 64];
        short8 nb3 = wb[((kt + 1) * 4 + 3) * 64];
        short8 af = cvt8(a0, a1);
        cf[0] = __builtin_amdgcn_mfma_f32_16x16x32_bf16(af, b0, cf[0], 0, 0, 0);
        cf[1] = __builtin_amdgcn_mfma_f32_16x16x32_bf16(af, b1, cf[1], 0, 0, 0);
        cf[2] = __builtin_amdgcn_mfma_f32_16x16x32_bf16(af, b2, cf[2], 0, 0, 0);
        cf[3] = __builtin_amdgcn_mfma_f32_16x16x32_bf16(af, b3, cf[3], 0, 0, 0);
        a0 = na0; a1 = na1; b0 = nb0; b1 = nb1; b2 = nb2; b3 = nb3;
    }
    {
        short8 af = cvt8(a0, a1);
        cf[0] = __builtin_amdgcn_mfma_f32_16x16x32_bf16(af, b0, cf[0], 0, 0, 0);
        cf[1] = __builtin_amdgcn_mfma_f32_16x16x32_bf16(af, b1, cf[1], 0, 0, 0);
        cf[2] = __builtin_amdgcn_mfma_f32_16x16x32_bf16(af, b2, cf[2], 0, 0, 0);
        cf[3] = __builtin_amdgcn_mfma_f32_16x16x32_bf16(af, b3, cf[3], 0, 0, 0);
    }

    #pragma unroll
    for (int r = 0; r < 4; ++r) {
        const int item = i0 + q * 4 + r;
        const int cat  = icat[item];
        const size_t eb = (size_t)item * 64;
        const size_t abn = (size_t)(NU + item) * 64;
        #pragma unroll
        for (int td = 0; td < 4; ++td) {
            const int d = td * 16 + m16;
            A[abn + d] = cf[td][r] + item_emb[eb + d] + cat_emb[cat * 64 + d];
        }
    }
}

// ---------------------------------------------------------------------------
// CSR build: histogram -> 2-level exclusive scan -> binned 2-pass scatter
// ---------------------------------------------------------------------------
__global__ __launch_bounds__(256) void hist_k(
    const int* __restrict__ row, int* __restrict__ counts)
{
    int e = blockIdx.x * 256 + threadIdx.x;
    if (e < NE) atomicAdd(&counts[row[e]], 1);
}

__global__ __launch_bounds__(256) void scan1_k(
    const int* __restrict__ counts, int* __restrict__ offs,
    int* __restrict__ blksum)
{
    __shared__ int s[256];
    int t = threadIdx.x;
    int base = blockIdx.x * 1024 + t * 4;
    int c0 = 0, c1 = 0, c2 = 0, c3 = 0;
    if (base + 3 < NN) {
        int4 c = *(const int4*)&counts[base];
        c0 = c.x; c1 = c.y; c2 = c.z; c3 = c.w;
    } else {
        if (base + 0 < NN) c0 = counts[base + 0];
        if (base + 1 < NN) c1 = counts[base + 1];
        if (base + 2 < NN) c2 = counts[base + 2];
    }
    int tsum = c0 + c1 + c2 + c3;
    s[t] = tsum;
    __syncthreads();
    for (int d = 1; d < 256; d <<= 1) {
        int v = (t >= d) ? s[t - d] : 0;
        __syncthreads();
        s[t] += v;
        __syncthreads();
    }
    if (t == 255) blksum[blockIdx.x] = s[255];
    int e0 = s[t] - tsum, e1 = e0 + c0, e2 = e1 + c1, e3 = e2 + c2;
    if (base + 0 < NN) offs[base + 0] = e0;
    if (base + 1 < NN) offs[base + 1] = e1;
    if (base + 2 < NN) offs[base + 2] = e2;
    if (base + 3 < NN) offs[base + 3] = e3;
}

__global__ __launch_bounds__(512) void scan2_k(int* __restrict__ blksum)
{
    __shared__ int s[512];
    int t = threadIdx.x;
    int v = (t < SCAN1_BLOCKS) ? blksum[t] : 0;
    s[t] = v;
    __syncthreads();
    for (int d = 1; d < 512; d <<= 1) {
        int x = (t >= d) ? s[t - d] : 0;
        __syncthreads();
        s[t] += x;
        __syncthreads();
    }
    if (t < SCAN1_BLOCKS) blksum[t] = s[t] - v;
}

__global__ __launch_bounds__(256) void addoff_k(
    int* __restrict__ offs, const int* __restrict__ blkoff,
    int* __restrict__ cursor,
    int* __restrict__ binstart, int* __restrict__ bincur)
{
    int i = blockIdx.x * 256 + threadIdx.x;
    if (i < NN) {
        int o = offs[i] + blkoff[i >> 10];
        offs[i] = o;
        cursor[i] = o;
        if ((i & 1023) == 0) {          // bin boundary: rows [b*1024,(b+1)*1024)
            binstart[i >> 10] = o;
            bincur[i >> 10] = o;
        }
    }
}

// ---------------------------------------------------------------------------
// Pass 1: block-level counting sort of 4096-edge chunks into 1024-row bins.
// ---------------------------------------------------------------------------
__global__ __launch_bounds__(256) void binscat_k(
    const int* __restrict__ row, const int* __restrict__ col,
    const float* __restrict__ val,
    int* __restrict__ bincur,
    int2* __restrict__ tcv, int* __restrict__ trow)
{
    __shared__ int lhist[512];   // padded bin histogram / counts
    __shared__ int lexcl[512];   // local exclusive offsets
    __shared__ int lbase[512];   // global base per bin for this block
    __shared__ int s[256];
    __shared__ int2 scv[CH];     // bin-sorted (col,val)
    __shared__ int  srow[CH];    // bin-sorted row

    int t = threadIdx.x;
    int e0 = blockIdx.x * CH;
    int n = NE - e0; if (n > CH) n = CH;

    lhist[t] = 0; lhist[t + 256] = 0;
    __syncthreads();

    int r[16]; int2 cv[16]; int rk[16];
    #pragma unroll
    for (int i = 0; i < 16; ++i) {
        int idx = e0 + i * 256 + t;
        if (idx < NE) {
            r[i] = row[idx];
            cv[i].x = col[idx];
            cv[i].y = __float_as_int(val[idx]);
            rk[i] = atomicAdd(&lhist[r[i] >> 10], 1);   // rank within bin
        }
    }
    __syncthreads();

    // exclusive scan over 512 padded bins, 2 per thread
    int c0 = lhist[2 * t], c1 = lhist[2 * t + 1];
    int tsum = c0 + c1;
    s[t] = tsum;
    __syncthreads();
    for (int d = 1; d < 256; d <<= 1) {
        int v = (t >= d) ? s[t - d] : 0;
        __syncthreads();
        s[t] += v;
        __syncthreads();
    }
    int ex = s[t] - tsum;
    lexcl[2 * t] = ex; lexcl[2 * t + 1] = ex + c0;
    // one global allocation per non-empty bin
    if (2 * t < NBINS && c0 > 0)     lbase[2 * t]     = atomicAdd(&bincur[2 * t], c0);
    if (2 * t + 1 < NBINS && c1 > 0) lbase[2 * t + 1] = atomicAdd(&bincur[2 * t + 1], c1);
    __syncthreads();

    // scatter into LDS at bin-sorted positions
    #pragma unroll
    for (int i = 0; i < 16; ++i) {
        int idx = e0 + i * 256 + t;
        if (idx < NE) {
            int b = r[i] >> 10;
            int p = lexcl[b] + rk[i];
            scv[p] = cv[i];
            srow[p] = r[i];
        }
    }
    __syncthreads();

    // write out: consecutive p -> consecutive global addresses per bin run
    for (int p = t; p < n; p += 256) {
        int rr = srow[p];
        int b = rr >> 10;
        int g = lbase[b] + (p - lexcl[b]);
        tcv[g] = scv[p];
        trow[g] = rr;
    }
}

// ---------------------------------------------------------------------------
// Pass 2: one block per bin; LDS staging so the final edges write is a
// fully coalesced stream over the bin's CSR range.
// ---------------------------------------------------------------------------
__global__ __launch_bounds__(256) void scatter2_k(
    const int2* __restrict__ tcv, const int* __restrict__ trow,
    const int* __restrict__ binstart,
    int* __restrict__ cursor, int2* __restrict__ edges)
{
    __shared__ int2 scv[P2CAP];
    int b = blockIdx.x;
    int s = binstart[b];
    int e = (b + 1 < NBINS) ? binstart[b + 1] : NE;
    int cnt = e - s;

    if (cnt <= P2CAP) {
        for (int p = s + threadIdx.x; p < e; p += 256) {
            int rr = trow[p];
            int pos = atomicAdd(&cursor[rr], 1);
            scv[pos - s] = tcv[p];
        }
        __syncthreads();
        for (int p = threadIdx.x; p < cnt; p += 256)
            edges[s + p] = scv[p];
    } else {
        // safety fallback (never expected with uniform rows)
        for (int p = s + threadIdx.x; p < e; p += 256) {
            int rr = trow[p];
            int pos = atomicAdd(&cursor[rr], 1);
            edges[pos] = tcv[p];
        }
    }
}

// ---------------------------------------------------------------------------
// CSR gather SpMM, 4-way unrolled for memory-level parallelism.
// ---------------------------------------------------------------------------
__global__ __launch_bounds__(256) void spmm_csr_k(
    const float4* __restrict__ x,
    float4* __restrict__ y,
    float4* __restrict__ out,
    const int* __restrict__ offs,
    const int* __restrict__ ends,
    const int2* __restrict__ edges,
    int mode)
{
    int t = threadIdx.x;
    int r = blockIdx.x * 16 + (t >> 4);
    int q = t & 15;
    int s = offs[r], e = ends[r];
    float4 acc = make_float4(0.f, 0.f, 0.f, 0.f);
    int k = s;
    for (; k + 4 <= e; k += 4) {
        int2 c0 = edges[k + 0];
        int2 c1 = edges[k + 1];
        int2 c2 = edges[k + 2];
        int2 c3 = edges[k + 3];
        float4 x0 = x[c0.x * 16 + q];
        float4 x1 = x[c1.x * 16 + q];
        float4 x2 = x[c2.x * 16 + q];
        float4 x3 = x[c3.x * 16 + q];
        fma4(acc, __int_as_float(c0.y), x0);
        fma4(acc, __int_as_float(c1.y), x1);
        fma4(acc, __int_as_float(c2.y), x2);
        fma4(acc, __int_as_float(c3.y), x3);
    }
    for (; k < e; ++k) {
        int2 cv = edges[k];
        fma4(acc, __int_as_float(cv.y), x[cv.x * 16 + q]);
    }
    int oi = r * 16 + q;
    if (mode != 3) y[oi] = acc;
    float4 o;
    if (mode == 1) {
        float4 xr = x[oi];
        o = make_float4(0.25f * (xr.x + acc.x), 0.25f * (xr.y + acc.y),
                        0.25f * (xr.z + acc.z), 0.25f * (xr.w + acc.w));
    } else {
        o = out[oi];
        o.x = fmaf(0.25f, acc.x, o.x);
        o.y = fmaf(0.25f, acc.y, o.y);
        o.z = fmaf(0.25f, acc.z, o.z);
        o.w = fmaf(0.25f, acc.w, o.w);
    }
    out[oi] = o;
}

// ---------------------------------------------------------------------------
extern "C" void kernel_launch(void* const* d_in, const int* in_sizes, int n_in,
                              void* d_out, int out_size, void* d_ws, size_t ws_size,
                              hipStream_t stream)
{
    const float* user_emb    = (const float*)d_in[0];
    const float* item_emb    = (const float*)d_in[1];
    const float* gender_emb  = (const float*)d_in[2];
    const float* age_emb     = (const float*)d_in[3];
    const float* cat_emb     = (const float*)d_in[4];
    const float* bert_w      = (const float*)d_in[5];
    const float* item_bert   = (const float*)d_in[6];
    const float* adj_val     = (const float*)d_in[7];
    const int*   user_gender = (const int*)d_in[8];
    const int*   user_age    = (const int*)d_in[9];
    const int*   item_cat    = (const int*)d_in[10];
    const int*   adj_row     = (const int*)d_in[11];
    const int*   adj_col     = (const int*)d_in[12];

    float* out = (float*)d_out;

    // workspace layout (all 16B aligned)
    float* A       = (float*)d_ws;                 // [NN*64]
    float* B       = A + (size_t)NN * 64;          // [NN*64]
    int2*  edges   = (int2*)(B + (size_t)NN * 64); // [NE]
    int*   offs    = (int*)(edges + NE);           // [NN] (also counts)
    int*   cursor  = offs + NN;                    // [NN]
    int*   blksum  = cursor + NN;                  // [512]
    int*   binstart= blksum + 512;                 // [512]
    int*   bincur  = binstart + 512;               // [512]
    short8* Wb     = (short8*)(bincur + 512);      // [3072] = 48 KB, 16B aligned

    // tmp binned edges alias into B (B is dead until spmm layer 1)
    int2* tcv  = (int2*)B;                         // [NE] 12 MB
    int*  trow = (int*)(tcv + NE);                 // [NE]  6 MB

    // --- CSR build ---
    hipMemsetAsync(offs, 0, (size_t)NN * sizeof(int), stream);
    hist_k<<<5860, 256, 0, stream>>>(adj_row, offs);
    scan1_k<<<SCAN1_BLOCKS, 256, 0, stream>>>(offs, offs, blksum);
    scan2_k<<<1, 512, 0, stream>>>(blksum);
    addoff_k<<<1172, 256, 0, stream>>>(offs, blksum, cursor, binstart, bincur);
    binscat_k<<<367, 256, 0, stream>>>(adj_row, adj_col, adj_val, bincur, tcv, trow);
    scatter2_k<<<NBINS, 256, 0, stream>>>(tcv, trow, binstart, cursor, edges);

    // --- layer-0 features into A (out contribution deferred to layer 1) ---
    wconv_k<<<12, 256, 0, stream>>>(bert_w, Wb);
    user_init_k<<<12500, 256, 0, stream>>>(
        (const float4*)user_emb, (const float4*)gender_emb, (const float4*)age_emb,
        user_gender, user_age, (float4*)A);
    item_init_k<<<1563, 256, 0, stream>>>(
        item_bert, Wb, item_emb, cat_emb, item_cat, A);

    // --- 3 propagation layers ---
    spmm_csr_k<<<18750, 256, 0, stream>>>(
        (const float4*)A, (float4*)B, (float4*)out, offs, cursor, edges, 1);
    spmm_csr_k<<<18750, 256, 0, stream>>>(
        (const float4*)B, (float4*)A, (float4*)out, offs, cursor, edges, 2);
    spmm_csr_k<<<18750, 256, 0, stream>>>(
        (const float4*)A, (float4*)B, (float4*)out, offs, cursor, edges, 3);
}

// Round 8
// 701.848 us; speedup vs baseline: 1.1122x; 1.0197x over previous
//
#include <hip/hip_runtime.h>
#include <hip/hip_bf16.h>

#define NU 200000
#define NI 100000
#define NN 300000
#define NE 1500000
#define BD 384

#define SCAN1_BLOCKS 293   // ceil(NN / 1024)
#define NBINS 293          // ceil(NN / 1024), 1024 rows per bin
#define CH 4096            // edges per binscat block (16 per thread)
#define P2CAP 6144         // pass-2 LDS staging capacity (avg bin = 5120)

typedef __attribute__((ext_vector_type(8))) short short8;
typedef __attribute__((ext_vector_type(4))) float floatx4;

// ---------------------------------------------------------------------------
__device__ __forceinline__ void fma4(float4& a, float s, const float4& w) {
    a.x = fmaf(s, w.x, a.x);
    a.y = fmaf(s, w.y, a.y);
    a.z = fmaf(s, w.z, a.z);
    a.w = fmaf(s, w.w, a.w);
}

// pack 8 fp32 -> 8 bf16 (RNE)
__device__ __forceinline__ short8 cvt8(const float4 a, const float4 b) {
    union { short8 v; __hip_bfloat16 e[8]; } u;
    u.e[0] = __float2bfloat16(a.x); u.e[1] = __float2bfloat16(a.y);
    u.e[2] = __float2bfloat16(a.z); u.e[3] = __float2bfloat16(a.w);
    u.e[4] = __float2bfloat16(b.x); u.e[5] = __float2bfloat16(b.y);
    u.e[6] = __float2bfloat16(b.z); u.e[7] = __float2bfloat16(b.w);
    return u.v;
}

// ---------------------------------------------------------------------------
// user rows: A[u] = user_emb + gender_emb[g] + age_emb[a]   (out deferred)
// ---------------------------------------------------------------------------
__global__ __launch_bounds__(256) void user_init_k(
    const float4* __restrict__ user_emb,
    const float4* __restrict__ gender_emb,
    const float4* __restrict__ age_emb,
    const int* __restrict__ ug,
    const int* __restrict__ ua,
    float4* __restrict__ A)
{
    int i = blockIdx.x * 256 + threadIdx.x;   // [0, NU*16)
    int u = i >> 4, q = i & 15;
    float4 e = user_emb[i];
    float4 g = gender_emb[ug[u] * 16 + q];
    float4 a = age_emb[ua[u] * 16 + q];
    e.x += g.x + a.x; e.y += g.y + a.y; e.z += g.z + a.z; e.w += g.w + a.w;
    A[i] = e;
}

// ---------------------------------------------------------------------------
// W fp32 [64][384] -> bf16 in MFMA B-fragment order:
//   Wb[(kt*4 + nt)*64 + lid] = short8{ W[nt*16 + m16][kt*32 + q*8 .. +7] }
//   where lid = q*16 + m16.  3072 entries of 16 B = 48 KB.
// ---------------------------------------------------------------------------
__global__ __launch_bounds__(256) void wconv_k(
    const float* __restrict__ W, short8* __restrict__ Wb)
{
    int t = blockIdx.x * 256 + threadIdx.x;   // entry index
    if (t >= 3072) return;
    int lid = t & 63, nt = (t >> 6) & 3, kt = t >> 8;
    int m16 = lid & 15, q = lid >> 4;
    const float* src = W + (size_t)(nt * 16 + m16) * BD + kt * 32 + q * 8;
    Wb[t] = cvt8(*(const float4*)src, *(const float4*)(src + 4));
}

// ---------------------------------------------------------------------------
// item rows via bf16 MFMA:
//   A[NU+i] = item_emb[i] + cat_emb[icat[i]] + bert[i] @ W^T
// B-frags come pre-converted + fragment-ordered from Wb (4 coalesced 16B/lane
// loads per K-step, L1/L2-resident). Only bert needs cvt (1 cvt8/K-step).
// Explicit depth-1 prefetch pipeline, fully unrolled (12 K-steps).
// ---------------------------------------------------------------------------
__global__ __launch_bounds__(256) void item_init_k(
    const float* __restrict__ bert,        // [NI][384]
    const short8* __restrict__ Wb,         // [3072] frag-ordered bf16 W
    const float* __restrict__ item_emb,    // [NI][64]
    const float* __restrict__ cat_emb,     // [11][64]
    const int* __restrict__ icat,
    float* __restrict__ A)                 // [NN][64]
{
    const int lid = threadIdx.x & 63;
    const int wv  = threadIdx.x >> 6;
    const int i0  = (blockIdx.x * 4 + wv) * 16;
    if (i0 >= NI) return;
    const int m16 = lid & 15;
    const int q   = lid >> 4;

    const float*  ab = bert + (size_t)(i0 + m16) * BD + q * 8;
    const short8* wb = Wb + lid;

    floatx4 cf[4];
    cf[0] = (floatx4){0.f, 0.f, 0.f, 0.f};
    cf[1] = cf[0]; cf[2] = cf[0]; cf[3] = cf[0];

    // prologue: K-step 0 in flight
    float4 a0 = *(const float4*)(ab + 0);
    float4 a1 = *(const float4*)(ab + 4);
    short8 b0 = wb[0 * 64];
    short8 b1 = wb[1 * 64];
    short8 b2 = wb[2 * 64];
    short8 b3 = wb[3 * 64];

    #pragma unroll
    for (int kt = 0; kt < 11; ++kt) {
        float4 na0 = *(const float4*)(ab + (kt + 1) * 32 + 0);
        float4 na1 = *(const float4*)(ab + (kt + 1) * 32 + 4);
        short8 nb0 = wb[((kt + 1) * 4 + 0) * 64];
        short8 nb1 = wb[((kt + 1) * 4 + 1) * 64];
        short8 nb2 = wb[((kt + 1) * 4 + 2) * 64];
        short8 nb3 = wb[((kt + 1) * 4 + 3) * 64];
        short8 af = cvt8(a0, a1);
        cf[0] = __builtin_amdgcn_mfma_f32_16x16x32_bf16(af, b0, cf[0], 0, 0, 0);
        cf[1] = __builtin_amdgcn_mfma_f32_16x16x32_bf16(af, b1, cf[1], 0, 0, 0);
        cf[2] = __builtin_amdgcn_mfma_f32_16x16x32_bf16(af, b2, cf[2], 0, 0, 0);
        cf[3] = __builtin_amdgcn_mfma_f32_16x16x32_bf16(af, b3, cf[3], 0, 0, 0);
        a0 = na0; a1 = na1; b0 = nb0; b1 = nb1; b2 = nb2; b3 = nb3;
    }
    {
        short8 af = cvt8(a0, a1);
        cf[0] = __builtin_amdgcn_mfma_f32_16x16x32_bf16(af, b0, cf[0], 0, 0, 0);
        cf[1] = __builtin_amdgcn_mfma_f32_16x16x32_bf16(af, b1, cf[1], 0, 0, 0);
        cf[2] = __builtin_amdgcn_mfma_f32_16x16x32_bf16(af, b2, cf[2], 0, 0, 0);
        cf[3] = __builtin_amdgcn_mfma_f32_16x16x32_bf16(af, b3, cf[3], 0, 0, 0);
    }

    #pragma unroll
    for (int r = 0; r < 4; ++r) {
        const int item = i0 + q * 4 + r;
        const int cat  = icat[item];
        const size_t eb = (size_t)item * 64;
        const size_t abn = (size_t)(NU + item) * 64;
        #pragma unroll
        for (int td = 0; td < 4; ++td) {
            const int d = td * 16 + m16;
            A[abn + d] = cf[td][r] + item_emb[eb + d] + cat_emb[cat * 64 + d];
        }
    }
}

// ---------------------------------------------------------------------------
// CSR build: histogram -> 2-level exclusive scan -> binned 2-pass scatter
// ---------------------------------------------------------------------------
__global__ __launch_bounds__(256) void hist_k(
    const int* __restrict__ row, int* __restrict__ counts)
{
    int e = blockIdx.x * 256 + threadIdx.x;
    if (e < NE) atomicAdd(&counts[row[e]], 1);
}

__global__ __launch_bounds__(256) void scan1_k(
    const int* __restrict__ counts, int* __restrict__ offs,
    int* __restrict__ blksum)
{
    __shared__ int s[256];
    int t = threadIdx.x;
    int base = blockIdx.x * 1024 + t * 4;
    int c0 = 0, c1 = 0, c2 = 0, c3 = 0;
    if (base + 3 < NN) {
        int4 c = *(const int4*)&counts[base];
        c0 = c.x; c1 = c.y; c2 = c.z; c3 = c.w;
    } else {
        if (base + 0 < NN) c0 = counts[base + 0];
        if (base + 1 < NN) c1 = counts[base + 1];
        if (base + 2 < NN) c2 = counts[base + 2];
    }
    int tsum = c0 + c1 + c2 + c3;
    s[t] = tsum;
    __syncthreads();
    for (int d = 1; d < 256; d <<= 1) {
        int v = (t >= d) ? s[t - d] : 0;
        __syncthreads();
        s[t] += v;
        __syncthreads();
    }
    if (t == 255) blksum[blockIdx.x] = s[255];
    int e0 = s[t] - tsum, e1 = e0 + c0, e2 = e1 + c1, e3 = e2 + c2;
    if (base + 0 < NN) offs[base + 0] = e0;
    if (base + 1 < NN) offs[base + 1] = e1;
    if (base + 2 < NN) offs[base + 2] = e2;
    if (base + 3 < NN) offs[base + 3] = e3;
}

__global__ __launch_bounds__(512) void scan2_k(int* __restrict__ blksum)
{
    __shared__ int s[512];
    int t = threadIdx.x;
    int v = (t < SCAN1_BLOCKS) ? blksum[t] : 0;
    s[t] = v;
    __syncthreads();
    for (int d = 1; d < 512; d <<= 1) {
        int x = (t >= d) ? s[t - d] : 0;
        __syncthreads();
        s[t] += x;
        __syncthreads();
    }
    if (t < SCAN1_BLOCKS) blksum[t] = s[t] - v;
}

__global__ __launch_bounds__(256) void addoff_k(
    int* __restrict__ offs, const int* __restrict__ blkoff,
    int* __restrict__ cursor,
    int* __restrict__ binstart, int* __restrict__ bincur)
{
    int i = blockIdx.x * 256 + threadIdx.x;
    if (i < NN) {
        int o = offs[i] + blkoff[i >> 10];
        offs[i] = o;
        cursor[i] = o;
        if ((i & 1023) == 0) {          // bin boundary: rows [b*1024,(b+1)*1024)
            binstart[i >> 10] = o;
            bincur[i >> 10] = o;
        }
    }
}

// ---------------------------------------------------------------------------
// Pass 1: block-level counting sort of 4096-edge chunks into 1024-row bins.
// ---------------------------------------------------------------------------
__global__ __launch_bounds__(256) void binscat_k(
    const int* __restrict__ row, const int* __restrict__ col,
    const float* __restrict__ val,
    int* __restrict__ bincur,
    int2* __restrict__ tcv, int* __restrict__ trow)
{
    __shared__ int lhist[512];   // padded bin histogram / counts
    __shared__ int lexcl[512];   // local exclusive offsets
    __shared__ int lbase[512];   // global base per bin for this block
    __shared__ int s[256];
    __shared__ int2 scv[CH];     // bin-sorted (col,val)
    __shared__ int  srow[CH];    // bin-sorted row

    int t = threadIdx.x;
    int e0 = blockIdx.x * CH;
    int n = NE - e0; if (n > CH) n = CH;

    lhist[t] = 0; lhist[t + 256] = 0;
    __syncthreads();

    int r[16]; int2 cv[16]; int rk[16];
    #pragma unroll
    for (int i = 0; i < 16; ++i) {
        int idx = e0 + i * 256 + t;
        if (idx < NE) {
            r[i] = row[idx];
            cv[i].x = col[idx];
            cv[i].y = __float_as_int(val[idx]);
            rk[i] = atomicAdd(&lhist[r[i] >> 10], 1);   // rank within bin
        }
    }
    __syncthreads();

    // exclusive scan over 512 padded bins, 2 per thread
    int c0 = lhist[2 * t], c1 = lhist[2 * t + 1];
    int tsum = c0 + c1;
    s[t] = tsum;
    __syncthreads();
    for (int d = 1; d < 256; d <<= 1) {
        int v = (t >= d) ? s[t - d] : 0;
        __syncthreads();
        s[t] += v;
        __syncthreads();
    }
    int ex = s[t] - tsum;
    lexcl[2 * t] = ex; lexcl[2 * t + 1] = ex + c0;
    // one global allocation per non-empty bin
    if (2 * t < NBINS && c0 > 0)     lbase[2 * t]     = atomicAdd(&bincur[2 * t], c0);
    if (2 * t + 1 < NBINS && c1 > 0) lbase[2 * t + 1] = atomicAdd(&bincur[2 * t + 1], c1);
    __syncthreads();

    // scatter into LDS at bin-sorted positions
    #pragma unroll
    for (int i = 0; i < 16; ++i) {
        int idx = e0 + i * 256 + t;
        if (idx < NE) {
            int b = r[i] >> 10;
            int p = lexcl[b] + rk[i];
            scv[p] = cv[i];
            srow[p] = r[i];
        }
    }
    __syncthreads();

    // write out: consecutive p -> consecutive global addresses per bin run
    for (int p = t; p < n; p += 256) {
        int rr = srow[p];
        int b = rr >> 10;
        int g = lbase[b] + (p - lexcl[b]);
        tcv[g] = scv[p];
        trow[g] = rr;
    }
}

// ---------------------------------------------------------------------------
// Pass 2: one block per bin; LDS staging so the final edges write is a
// fully coalesced stream over the bin's CSR range.
// ---------------------------------------------------------------------------
__global__ __launch_bounds__(256) void scatter2_k(
    const int2* __restrict__ tcv, const int* __restrict__ trow,
    const int* __restrict__ binstart,
    int* __restrict__ cursor, int2* __restrict__ edges)
{
    __shared__ int2 scv[P2CAP];
    int b = blockIdx.x;
    int s = binstart[b];
    int e = (b + 1 < NBINS) ? binstart[b + 1] : NE;
    int cnt = e - s;

    if (cnt <= P2CAP) {
        for (int p = s + threadIdx.x; p < e; p += 256) {
            int rr = trow[p];
            int pos = atomicAdd(&cursor[rr], 1);
            scv[pos - s] = tcv[p];
        }
        __syncthreads();
        for (int p = threadIdx.x; p < cnt; p += 256)
            edges[s + p] = scv[p];
    } else {
        // safety fallback (never expected with uniform rows)
        for (int p = s + threadIdx.x; p < e; p += 256) {
            int rr = trow[p];
            int pos = atomicAdd(&cursor[rr], 1);
            edges[pos] = tcv[p];
        }
    }
}

// ---------------------------------------------------------------------------
// CSR gather SpMM, 4-way unrolled for memory-level parallelism.
// mode 1 (layer 1): y[r]=acc; out[r] = 0.25*(x[r]+acc)     -> out=0.25(x0+x1)
// mode 2 (layer 2): y[r]=acc only (no out access)
// mode 3 (layer 3): out[r] += 0.25*(x[r]+acc)  -- x IS x2, acc IS x3, so this
//                   folds both remaining layer terms into one RMW.
// ---------------------------------------------------------------------------
__global__ __launch_bounds__(256) void spmm_csr_k(
    const float4* __restrict__ x,
    float4* __restrict__ y,
    float4* __restrict__ out,
    const int* __restrict__ offs,
    const int* __restrict__ ends,
    const int2* __restrict__ edges,
    int mode)
{
    int t = threadIdx.x;
    int r = blockIdx.x * 16 + (t >> 4);
    int q = t & 15;
    int s = offs[r], e = ends[r];
    float4 acc = make_float4(0.f, 0.f, 0.f, 0.f);
    int k = s;
    for (; k + 4 <= e; k += 4) {
        int2 c0 = edges[k + 0];
        int2 c1 = edges[k + 1];
        int2 c2 = edges[k + 2];
        int2 c3 = edges[k + 3];
        float4 x0 = x[c0.x * 16 + q];
        float4 x1 = x[c1.x * 16 + q];
        float4 x2 = x[c2.x * 16 + q];
        float4 x3 = x[c3.x * 16 + q];
        fma4(acc, __int_as_float(c0.y), x0);
        fma4(acc, __int_as_float(c1.y), x1);
        fma4(acc, __int_as_float(c2.y), x2);
        fma4(acc, __int_as_float(c3.y), x3);
    }
    for (; k < e; ++k) {
        int2 cv = edges[k];
        fma4(acc, __int_as_float(cv.y), x[cv.x * 16 + q]);
    }
    int oi = r * 16 + q;
    if (mode != 3) y[oi] = acc;
    if (mode == 2) return;
    float4 o;
    if (mode == 1) {
        float4 xr = x[oi];
        o = make_float4(0.25f * (xr.x + acc.x), 0.25f * (xr.y + acc.y),
                        0.25f * (xr.z + acc.z), 0.25f * (xr.w + acc.w));
    } else {
        float4 xr = x[oi];
        o = out[oi];
        o.x += 0.25f * (xr.x + acc.x);
        o.y += 0.25f * (xr.y + acc.y);
        o.z += 0.25f * (xr.z + acc.z);
        o.w += 0.25f * (xr.w + acc.w);
    }
    out[oi] = o;
}

// ---------------------------------------------------------------------------
extern "C" void kernel_launch(void* const* d_in, const int* in_sizes, int n_in,
                              void* d_out, int out_size, void* d_ws, size_t ws_size,
                              hipStream_t stream)
{
    const float* user_emb    = (const float*)d_in[0];
    const float* item_emb    = (const float*)d_in[1];
    const float* gender_emb  = (const float*)d_in[2];
    const float* age_emb     = (const float*)d_in[3];
    const float* cat_emb     = (const float*)d_in[4];
    const float* bert_w      = (const float*)d_in[5];
    const float* item_bert   = (const float*)d_in[6];
    const float* adj_val     = (const float*)d_in[7];
    const int*   user_gender = (const int*)d_in[8];
    const int*   user_age    = (const int*)d_in[9];
    const int*   item_cat    = (const int*)d_in[10];
    const int*   adj_row     = (const int*)d_in[11];
    const int*   adj_col     = (const int*)d_in[12];

    float* out = (float*)d_out;

    // workspace layout (all 16B aligned)
    float* A       = (float*)d_ws;                 // [NN*64]
    float* B       = A + (size_t)NN * 64;          // [NN*64]
    int2*  edges   = (int2*)(B + (size_t)NN * 64); // [NE]
    int*   offs    = (int*)(edges + NE);           // [NN] (also counts)
    int*   cursor  = offs + NN;                    // [NN]
    int*   blksum  = cursor + NN;                  // [512]
    int*   binstart= blksum + 512;                 // [512]
    int*   bincur  = binstart + 512;               // [512]
    short8* Wb     = (short8*)(bincur + 512);      // [3072] = 48 KB, 16B aligned

    // tmp binned edges alias into B (B is dead until spmm layer 1)
    int2* tcv  = (int2*)B;                         // [NE] 12 MB
    int*  trow = (int*)(tcv + NE);                 // [NE]  6 MB

    // --- CSR build ---
    hipMemsetAsync(offs, 0, (size_t)NN * sizeof(int), stream);
    hist_k<<<5860, 256, 0, stream>>>(adj_row, offs);
    scan1_k<<<SCAN1_BLOCKS, 256, 0, stream>>>(offs, offs, blksum);
    scan2_k<<<1, 512, 0, stream>>>(blksum);
    addoff_k<<<1172, 256, 0, stream>>>(offs, blksum, cursor, binstart, bincur);
    binscat_k<<<367, 256, 0, stream>>>(adj_row, adj_col, adj_val, bincur, tcv, trow);
    scatter2_k<<<NBINS, 256, 0, stream>>>(tcv, trow, binstart, cursor, edges);

    // --- layer-0 features into A (out contribution deferred to layer 1) ---
    wconv_k<<<12, 256, 0, stream>>>(bert_w, Wb);
    user_init_k<<<12500, 256, 0, stream>>>(
        (const float4*)user_emb, (const float4*)gender_emb, (const float4*)age_emb,
        user_gender, user_age, (float4*)A);
    item_init_k<<<1563, 256, 0, stream>>>(
        item_bert, Wb, item_emb, cat_emb, item_cat, A);

    // --- 3 propagation layers ---
    spmm_csr_k<<<18750, 256, 0, stream>>>(
        (const float4*)A, (float4*)B, (float4*)out, offs, cursor, edges, 1);
    spmm_csr_k<<<18750, 256, 0, stream>>>(
        (const float4*)B, (float4*)A, (float4*)out, offs, cursor, edges, 2);
    spmm_csr_k<<<18750, 256, 0, stream>>>(
        (const float4*)A, (float4*)B, (float4*)out, offs, cursor, edges, 3);
}

// Round 12
// 651.648 us; speedup vs baseline: 1.1979x; 1.0770x over previous
//
#include <hip/hip_runtime.h>
#include <hip/hip_bf16.h>

#define NU 200000
#define NI 100000
#define NN 300000
#define NE 1500000
#define BD 384

#define SCAN1_BLOCKS 293   // ceil(NN / 1024)
#define NBINS 293          // ceil(NN / 1024), 1024 rows per bin
#define CH 4096            // edges per binscat block (16 per thread)
#define P2CAP 6144         // pass-2 LDS staging capacity (avg bin = 5120)

typedef __attribute__((ext_vector_type(8))) short short8;
typedef __attribute__((ext_vector_type(4))) float floatx4;

// ---------------------------------------------------------------------------
__device__ __forceinline__ void fma4(float4& a, float s, const float4& w) {
    a.x = fmaf(s, w.x, a.x);
    a.y = fmaf(s, w.y, a.y);
    a.z = fmaf(s, w.z, a.z);
    a.w = fmaf(s, w.w, a.w);
}

// bf16 (as ushort) -> fp32
__device__ __forceinline__ float bf2f(unsigned short v) {
    union { unsigned int u; float f; } c; c.u = ((unsigned int)v) << 16; return c.f;
}
__device__ __forceinline__ float4 ub4f(const ushort4 v) {
    return make_float4(bf2f(v.x), bf2f(v.y), bf2f(v.z), bf2f(v.w));
}
// fp32x4 -> bf16x4 (RNE)
__device__ __forceinline__ ushort4 f4bf(const float4 a) {
    union { __hip_bfloat16 b; unsigned short u; } c0, c1, c2, c3;
    c0.b = __float2bfloat16(a.x); c1.b = __float2bfloat16(a.y);
    c2.b = __float2bfloat16(a.z); c3.b = __float2bfloat16(a.w);
    return make_ushort4(c0.u, c1.u, c2.u, c3.u);
}

// pack 8 fp32 -> 8 bf16 (RNE)
__device__ __forceinline__ short8 cvt8(const float4 a, const float4 b) {
    union { short8 v; __hip_bfloat16 e[8]; } u;
    u.e[0] = __float2bfloat16(a.x); u.e[1] = __float2bfloat16(a.y);
    u.e[2] = __float2bfloat16(a.z); u.e[3] = __float2bfloat16(a.w);
    u.e[4] = __float2bfloat16(b.x); u.e[5] = __float2bfloat16(b.y);
    u.e[6] = __float2bfloat16(b.z); u.e[7] = __float2bfloat16(b.w);
    return u.v;
}

// ---------------------------------------------------------------------------
// user rows: A[u] = user_emb + gender_emb[g] + age_emb[a]   (out deferred)
// ---------------------------------------------------------------------------
__global__ __launch_bounds__(256) void user_init_k(
    const float4* __restrict__ user_emb,
    const float4* __restrict__ gender_emb,
    const float4* __restrict__ age_emb,
    const int* __restrict__ ug,
    const int* __restrict__ ua,
    float4* __restrict__ A)
{
    int i = blockIdx.x * 256 + threadIdx.x;   // [0, NU*16)
    int u = i >> 4, q = i & 15;
    float4 e = user_emb[i];
    float4 g = gender_emb[ug[u] * 16 + q];
    float4 a = age_emb[ua[u] * 16 + q];
    e.x += g.x + a.x; e.y += g.y + a.y; e.z += g.z + a.z; e.w += g.w + a.w;
    A[i] = e;
}

// ---------------------------------------------------------------------------
// W fp32 [64][384] -> bf16 in MFMA B-fragment order.
// ---------------------------------------------------------------------------
__global__ __launch_bounds__(256) void wconv_k(
    const float* __restrict__ W, short8* __restrict__ Wb)
{
    int t = blockIdx.x * 256 + threadIdx.x;   // entry index
    if (t >= 3072) return;
    int lid = t & 63, nt = (t >> 6) & 3, kt = t >> 8;
    int m16 = lid & 15, q = lid >> 4;
    const float* src = W + (size_t)(nt * 16 + m16) * BD + kt * 32 + q * 8;
    Wb[t] = cvt8(*(const float4*)src, *(const float4*)(src + 4));
}

// ---------------------------------------------------------------------------
// item rows via bf16 MFMA:
//   A[NU+i] = item_emb[i] + cat_emb[icat[i]] + bert[i] @ W^T
// ---------------------------------------------------------------------------
__global__ __launch_bounds__(256) void item_init_k(
    const float* __restrict__ bert,        // [NI][384]
    const short8* __restrict__ Wb,         // [3072] frag-ordered bf16 W
    const float* __restrict__ item_emb,    // [NI][64]
    const float* __restrict__ cat_emb,     // [11][64]
    const int* __restrict__ icat,
    float* __restrict__ A)                 // [NN][64]
{
    const int lid = threadIdx.x & 63;
    const int wv  = threadIdx.x >> 6;
    const int i0  = (blockIdx.x * 4 + wv) * 16;
    if (i0 >= NI) return;
    const int m16 = lid & 15;
    const int q   = lid >> 4;

    const float*  ab = bert + (size_t)(i0 + m16) * BD + q * 8;
    const short8* wb = Wb + lid;

    floatx4 cf[4];
    cf[0] = (floatx4){0.f, 0.f, 0.f, 0.f};
    cf[1] = cf[0]; cf[2] = cf[0]; cf[3] = cf[0];

    // prologue: K-step 0 in flight
    float4 a0 = *(const float4*)(ab + 0);
    float4 a1 = *(const float4*)(ab + 4);
    short8 b0 = wb[0 * 64];
    short8 b1 = wb[1 * 64];
    short8 b2 = wb[2 * 64];
    short8 b3 = wb[3 * 64];

    #pragma unroll
    for (int kt = 0; kt < 11; ++kt) {
        float4 na0 = *(const float4*)(ab + (kt + 1) * 32 + 0);
        float4 na1 = *(const float4*)(ab + (kt + 1) * 32 + 4);
        short8 nb0 = wb[((kt + 1) * 4 + 0) * 64];
        short8 nb1 = wb[((kt + 1) * 4 + 1) * 64];
        short8 nb2 = wb[((kt + 1) * 4 + 2) * 64];
        short8 nb3 = wb[((kt + 1) * 4 + 3) * 64];
        short8 af = cvt8(a0, a1);
        cf[0] = __builtin_amdgcn_mfma_f32_16x16x32_bf16(af, b0, cf[0], 0, 0, 0);
        cf[1] = __builtin_amdgcn_mfma_f32_16x16x32_bf16(af, b1, cf[1], 0, 0, 0);
        cf[2] = __builtin_amdgcn_mfma_f32_16x16x32_bf16(af, b2, cf[2], 0, 0, 0);
        cf[3] = __builtin_amdgcn_mfma_f32_16x16x32_bf16(af, b3, cf[3], 0, 0, 0);
        a0 = na0; a1 = na1; b0 = nb0; b1 = nb1; b2 = nb2; b3 = nb3;
    }
    {
        short8 af = cvt8(a0, a1);
        cf[0] = __builtin_amdgcn_mfma_f32_16x16x32_bf16(af, b0, cf[0], 0, 0, 0);
        cf[1] = __builtin_amdgcn_mfma_f32_16x16x32_bf16(af, b1, cf[1], 0, 0, 0);
        cf[2] = __builtin_amdgcn_mfma_f32_16x16x32_bf16(af, b2, cf[2], 0, 0, 0);
        cf[3] = __builtin_amdgcn_mfma_f32_16x16x32_bf16(af, b3, cf[3], 0, 0, 0);
    }

    #pragma unroll
    for (int r = 0; r < 4; ++r) {
        const int item = i0 + q * 4 + r;
        const int cat  = icat[item];
        const size_t eb = (size_t)item * 64;
        const size_t abn = (size_t)(NU + item) * 64;
        #pragma unroll
        for (int td = 0; td < 4; ++td) {
            const int d = td * 16 + m16;
            A[abn + d] = cf[td][r] + item_emb[eb + d] + cat_emb[cat * 64 + d];
        }
    }
}

// ---------------------------------------------------------------------------
// CSR build: histogram -> 2-level exclusive scan -> binned 2-pass scatter
// ---------------------------------------------------------------------------
__global__ __launch_bounds__(256) void hist_k(
    const int* __restrict__ row, int* __restrict__ counts)
{
    int e = blockIdx.x * 256 + threadIdx.x;
    if (e < NE) atomicAdd(&counts[row[e]], 1);
}

__global__ __launch_bounds__(256) void scan1_k(
    const int* __restrict__ counts, int* __restrict__ offs,
    int* __restrict__ blksum)
{
    __shared__ int s[256];
    int t = threadIdx.x;
    int base = blockIdx.x * 1024 + t * 4;
    int c0 = 0, c1 = 0, c2 = 0, c3 = 0;
    if (base + 3 < NN) {
        int4 c = *(const int4*)&counts[base];
        c0 = c.x; c1 = c.y; c2 = c.z; c3 = c.w;
    } else {
        if (base + 0 < NN) c0 = counts[base + 0];
        if (base + 1 < NN) c1 = counts[base + 1];
        if (base + 2 < NN) c2 = counts[base + 2];
    }
    int tsum = c0 + c1 + c2 + c3;
    s[t] = tsum;
    __syncthreads();
    for (int d = 1; d < 256; d <<= 1) {
        int v = (t >= d) ? s[t - d] : 0;
        __syncthreads();
        s[t] += v;
        __syncthreads();
    }
    if (t == 255) blksum[blockIdx.x] = s[255];
    int e0 = s[t] - tsum, e1 = e0 + c0, e2 = e1 + c1, e3 = e2 + c2;
    if (base + 0 < NN) offs[base + 0] = e0;
    if (base + 1 < NN) offs[base + 1] = e1;
    if (base + 2 < NN) offs[base + 2] = e2;
    if (base + 3 < NN) offs[base + 3] = e3;
}

__global__ __launch_bounds__(512) void scan2_k(int* __restrict__ blksum)
{
    __shared__ int s[512];
    int t = threadIdx.x;
    int v = (t < SCAN1_BLOCKS) ? blksum[t] : 0;
    s[t] = v;
    __syncthreads();
    for (int d = 1; d < 512; d <<= 1) {
        int x = (t >= d) ? s[t - d] : 0;
        __syncthreads();
        s[t] += x;
        __syncthreads();
    }
    if (t < SCAN1_BLOCKS) blksum[t] = s[t] - v;
}

__global__ __launch_bounds__(256) void addoff_k(
    int* __restrict__ offs, const int* __restrict__ blkoff,
    int* __restrict__ cursor,
    int* __restrict__ binstart, int* __restrict__ bincur)
{
    int i = blockIdx.x * 256 + threadIdx.x;
    if (i < NN) {
        int o = offs[i] + blkoff[i >> 10];
        offs[i] = o;
        cursor[i] = o;
        if ((i & 1023) == 0) {          // bin boundary: rows [b*1024,(b+1)*1024)
            binstart[i >> 10] = o;
            bincur[i >> 10] = o;
        }
    }
}

// ---------------------------------------------------------------------------
// Pass 1: block-level counting sort of 4096-edge chunks into 1024-row bins.
// ---------------------------------------------------------------------------
__global__ __launch_bounds__(256) void binscat_k(
    const int* __restrict__ row, const int* __restrict__ col,
    const float* __restrict__ val,
    int* __restrict__ bincur,
    int2* __restrict__ tcv, int* __restrict__ trow)
{
    __shared__ int lhist[512];   // padded bin histogram / counts
    __shared__ int lexcl[512];   // local exclusive offsets
    __shared__ int lbase[512];   // global base per bin for this block
    __shared__ int s[256];
    __shared__ int2 scv[CH];     // bin-sorted (col,val)
    __shared__ int  srow[CH];    // bin-sorted row

    int t = threadIdx.x;
    int e0 = blockIdx.x * CH;
    int n = NE - e0; if (n > CH) n = CH;

    lhist[t] = 0; lhist[t + 256] = 0;
    __syncthreads();

    int r[16]; int2 cv[16]; int rk[16];
    #pragma unroll
    for (int i = 0; i < 16; ++i) {
        int idx = e0 + i * 256 + t;
        if (idx < NE) {
            r[i] = row[idx];
            cv[i].x = col[idx];
            cv[i].y = __float_as_int(val[idx]);
            rk[i] = atomicAdd(&lhist[r[i] >> 10], 1);   // rank within bin
        }
    }
    __syncthreads();

    // exclusive scan over 512 padded bins, 2 per thread
    int c0 = lhist[2 * t], c1 = lhist[2 * t + 1];
    int tsum = c0 + c1;
    s[t] = tsum;
    __syncthreads();
    for (int d = 1; d < 256; d <<= 1) {
        int v = (t >= d) ? s[t - d] : 0;
        __syncthreads();
        s[t] += v;
        __syncthreads();
    }
    int ex = s[t] - tsum;
    lexcl[2 * t] = ex; lexcl[2 * t + 1] = ex + c0;
    // one global allocation per non-empty bin
    if (2 * t < NBINS && c0 > 0)     lbase[2 * t]     = atomicAdd(&bincur[2 * t], c0);
    if (2 * t + 1 < NBINS && c1 > 0) lbase[2 * t + 1] = atomicAdd(&bincur[2 * t + 1], c1);
    __syncthreads();

    // scatter into LDS at bin-sorted positions
    #pragma unroll
    for (int i = 0; i < 16; ++i) {
        int idx = e0 + i * 256 + t;
        if (idx < NE) {
            int b = r[i] >> 10;
            int p = lexcl[b] + rk[i];
            scv[p] = cv[i];
            srow[p] = r[i];
        }
    }
    __syncthreads();

    // write out: consecutive p -> consecutive global addresses per bin run
    for (int p = t; p < n; p += 256) {
        int rr = srow[p];
        int b = rr >> 10;
        int g = lbase[b] + (p - lexcl[b]);
        tcv[g] = scv[p];
        trow[g] = rr;
    }
}

// ---------------------------------------------------------------------------
// Pass 2: one block per bin; LDS staging so the final edges write is a
// fully coalesced stream over the bin's CSR range.
// ---------------------------------------------------------------------------
__global__ __launch_bounds__(256) void scatter2_k(
    const int2* __restrict__ tcv, const int* __restrict__ trow,
    const int* __restrict__ binstart,
    int* __restrict__ cursor, int2* __restrict__ edges)
{
    __shared__ int2 scv[P2CAP];
    int b = blockIdx.x;
    int s = binstart[b];
    int e = (b + 1 < NBINS) ? binstart[b + 1] : NE;
    int cnt = e - s;

    if (cnt <= P2CAP) {
        for (int p = s + threadIdx.x; p < e; p += 256) {
            int rr = trow[p];
            int pos = atomicAdd(&cursor[rr], 1);
            scv[pos - s] = tcv[p];
        }
        __syncthreads();
        for (int p = threadIdx.x; p < cnt; p += 256)
            edges[s + p] = scv[p];
    } else {
        // safety fallback (never expected with uniform rows)
        for (int p = s + threadIdx.x; p < e; p += 256) {
            int rr = trow[p];
            int pos = atomicAdd(&cursor[rr], 1);
            edges[pos] = tcv[p];
        }
    }
}

// ---------------------------------------------------------------------------
// SpMM layer 1: gather fp32 x0 (A), write y = x1 as bf16, out = 0.25(x0+x1).
// 16 lanes/row (float4 gather each), 16 rows/block.
// ---------------------------------------------------------------------------
__global__ __launch_bounds__(256) void spmm_l1_k(
    const float4* __restrict__ x,        // fp32 x0
    ushort4* __restrict__ yb,            // bf16 x1 out
    float4* __restrict__ out,
    const int* __restrict__ offs,
    const int* __restrict__ ends,
    const int2* __restrict__ edges)
{
    int t = threadIdx.x;
    int r = blockIdx.x * 16 + (t >> 4);
    int q = t & 15;
    int s = offs[r], e = ends[r];
    float4 acc = make_float4(0.f, 0.f, 0.f, 0.f);
    int k = s;
    for (; k + 4 <= e; k += 4) {
        int2 c0 = edges[k + 0];
        int2 c1 = edges[k + 1];
        int2 c2 = edges[k + 2];
        int2 c3 = edges[k + 3];
        float4 x0 = x[c0.x * 16 + q];
        float4 x1 = x[c1.x * 16 + q];
        float4 x2 = x[c2.x * 16 + q];
        float4 x3 = x[c3.x * 16 + q];
        fma4(acc, __int_as_float(c0.y), x0);
        fma4(acc, __int_as_float(c1.y), x1);
        fma4(acc, __int_as_float(c2.y), x2);
        fma4(acc, __int_as_float(c3.y), x3);
    }
    for (; k < e; ++k) {
        int2 cv = edges[k];
        fma4(acc, __int_as_float(cv.y), x[cv.x * 16 + q]);
    }
    int oi = r * 16 + q;
    yb[oi] = f4bf(acc);
    float4 xr = x[oi];
    out[oi] = make_float4(0.25f * (xr.x + acc.x), 0.25f * (xr.y + acc.y),
                          0.25f * (xr.z + acc.z), 0.25f * (xr.w + acc.w));
}

// ---------------------------------------------------------------------------
// SpMM layers 2/3 on bf16 x (128 B/row gather):
// mode 2: yb = acc (bf16), no out access.
// mode 3: out += 0.25*(x[oi] + acc)  (x IS x2, acc IS x3 — folds both terms).
// ---------------------------------------------------------------------------
__global__ __launch_bounds__(256) void spmm_bf_k(
    const ushort4* __restrict__ xb,      // bf16 gather source
    ushort4* __restrict__ yb,            // bf16 y (mode 2)
    float4* __restrict__ out,
    const int* __restrict__ offs,
    const int* __restrict__ ends,
    const int2* __restrict__ edges,
    int mode)
{
    int t = threadIdx.x;
    int r = blockIdx.x * 16 + (t >> 4);
    int q = t & 15;
    int s = offs[r], e = ends[r];
    float4 acc = make_float4(0.f, 0.f, 0.f, 0.f);
    int k = s;
    for (; k + 4 <= e; k += 4) {
        int2 c0 = edges[k + 0];
        int2 c1 = edges[k + 1];
        int2 c2 = edges[k + 2];
        int2 c3 = edges[k + 3];
        ushort4 v0 = xb[c0.x * 16 + q];
        ushort4 v1 = xb[c1.x * 16 + q];
        ushort4 v2 = xb[c2.x * 16 + q];
        ushort4 v3 = xb[c3.x * 16 + q];
        fma4(acc, __int_as_float(c0.y), ub4f(v0));
        fma4(acc, __int_as_float(c1.y), ub4f(v1));
        fma4(acc, __int_as_float(c2.y), ub4f(v2));
        fma4(acc, __int_as_float(c3.y), ub4f(v3));
    }
    for (; k < e; ++k) {
        int2 cv = edges[k];
        fma4(acc, __int_as_float(cv.y), ub4f(xb[cv.x * 16 + q]));
    }
    int oi = r * 16 + q;
    if (mode == 2) {
        yb[oi] = f4bf(acc);
    } else {
        float4 xr = ub4f(xb[oi]);
        float4 o = out[oi];
        o.x += 0.25f * (xr.x + acc.x);
        o.y += 0.25f * (xr.y + acc.y);
        o.z += 0.25f * (xr.z + acc.z);
        o.w += 0.25f * (xr.w + acc.w);
        out[oi] = o;
    }
}

// ---------------------------------------------------------------------------
extern "C" void kernel_launch(void* const* d_in, const int* in_sizes, int n_in,
                              void* d_out, int out_size, void* d_ws, size_t ws_size,
                              hipStream_t stream)
{
    const float* user_emb    = (const float*)d_in[0];
    const float* item_emb    = (const float*)d_in[1];
    const float* gender_emb  = (const float*)d_in[2];
    const float* age_emb     = (const float*)d_in[3];
    const float* cat_emb     = (const float*)d_in[4];
    const float* bert_w      = (const float*)d_in[5];
    const float* item_bert   = (const float*)d_in[6];
    const float* adj_val     = (const float*)d_in[7];
    const int*   user_gender = (const int*)d_in[8];
    const int*   user_age    = (const int*)d_in[9];
    const int*   item_cat    = (const int*)d_in[10];
    const int*   adj_row     = (const int*)d_in[11];
    const int*   adj_col     = (const int*)d_in[12];

    float* out = (float*)d_out;

    // workspace layout (all 16B aligned)
    float* A       = (float*)d_ws;                 // [NN*64] fp32 x0
    float* B       = A + (size_t)NN * 64;          // [NN*64] region, reused:
    int2*  edges   = (int2*)(B + (size_t)NN * 64); // [NE]
    int*   offs    = (int*)(edges + NE);           // [NN] (also counts)
    int*   cursor  = offs + NN;                    // [NN]
    int*   blksum  = cursor + NN;                  // [512]
    int*   binstart= blksum + 512;                 // [512]
    int*   bincur  = binstart + 512;               // [512]
    short8* Wb     = (short8*)(bincur + 512);      // [3072] = 48 KB, 16B aligned

    // B region overlays:
    //   during CSR build: tcv [NE] (12 MB) + trow [NE] (6 MB)
    //   during spmm:      B16 = bf16 x1 [NN*64] (38.4 MB) + A16 = bf16 x2 (38.4 MB)
    int2*    tcv  = (int2*)B;                      // [NE] 12 MB
    int*     trow = (int*)(tcv + NE);              // [NE]  6 MB
    ushort4* B16  = (ushort4*)B;                   // bf16 x1, 38.4 MB
    ushort4* A16  = B16 + (size_t)NN * 16;         // bf16 x2, 38.4 MB

    // --- CSR build ---
    hipMemsetAsync(offs, 0, (size_t)NN * sizeof(int), stream);
    hist_k<<<5860, 256, 0, stream>>>(adj_row, offs);
    scan1_k<<<SCAN1_BLOCKS, 256, 0, stream>>>(offs, offs, blksum);
    scan2_k<<<1, 512, 0, stream>>>(blksum);
    addoff_k<<<1172, 256, 0, stream>>>(offs, blksum, cursor, binstart, bincur);
    binscat_k<<<367, 256, 0, stream>>>(adj_row, adj_col, adj_val, bincur, tcv, trow);
    scatter2_k<<<NBINS, 256, 0, stream>>>(tcv, trow, binstart, cursor, edges);

    // --- layer-0 features into A (out contribution deferred to layer 1) ---
    wconv_k<<<12, 256, 0, stream>>>(bert_w, Wb);
    user_init_k<<<12500, 256, 0, stream>>>(
        (const float4*)user_emb, (const float4*)gender_emb, (const float4*)age_emb,
        user_gender, user_age, (float4*)A);
    item_init_k<<<1563, 256, 0, stream>>>(
        item_bert, Wb, item_emb, cat_emb, item_cat, A);

    // --- 3 propagation layers (intermediates x1/x2 in bf16) ---
    spmm_l1_k<<<18750, 256, 0, stream>>>(
        (const float4*)A, B16, (float4*)out, offs, cursor, edges);
    spmm_bf_k<<<18750, 256, 0, stream>>>(
        B16, A16, (float4*)out, offs, cursor, edges, 2);
    spmm_bf_k<<<18750, 256, 0, stream>>>(
        A16, B16, (float4*)out, offs, cursor, edges, 3);
}

// Round 14
// 624.181 us; speedup vs baseline: 1.2506x; 1.0440x over previous
//
#include <hip/hip_runtime.h>
#include <hip/hip_bf16.h>

#define NU 200000
#define NI 100000
#define NN 300000
#define NE 1500000
#define BD 384

#define SCAN1_BLOCKS 293   // ceil(NN / 1024)
#define NBINS 293          // ceil(NN / 1024), 1024 rows per bin
#define CH 4096            // edges per binscat block (16 per thread)
#define P2CAP 6144         // pass-2 LDS staging capacity (avg bin = 5120)

typedef __attribute__((ext_vector_type(8))) short short8;
typedef __attribute__((ext_vector_type(4))) float floatx4;

// ---------------------------------------------------------------------------
__device__ __forceinline__ void fma4(float4& a, float s, const float4& w) {
    a.x = fmaf(s, w.x, a.x);
    a.y = fmaf(s, w.y, a.y);
    a.z = fmaf(s, w.z, a.z);
    a.w = fmaf(s, w.w, a.w);
}

// bf16 (as ushort) -> fp32
__device__ __forceinline__ float bf2f(unsigned short v) {
    union { unsigned int u; float f; } c; c.u = ((unsigned int)v) << 16; return c.f;
}
__device__ __forceinline__ float4 ub4f(const ushort4 v) {
    return make_float4(bf2f(v.x), bf2f(v.y), bf2f(v.z), bf2f(v.w));
}
// fp32 -> bf16 bits (RNE)
__device__ __forceinline__ unsigned short f2bfu(float x) {
    union { __hip_bfloat16 b; unsigned short u; } c; c.b = __float2bfloat16(x); return c.u;
}
// fp32x4 -> bf16x4 (RNE)
__device__ __forceinline__ ushort4 f4bf(const float4 a) {
    return make_ushort4(f2bfu(a.x), f2bfu(a.y), f2bfu(a.z), f2bfu(a.w));
}

// pack 8 fp32 -> 8 bf16 (RNE)
__device__ __forceinline__ short8 cvt8(const float4 a, const float4 b) {
    union { short8 v; __hip_bfloat16 e[8]; } u;
    u.e[0] = __float2bfloat16(a.x); u.e[1] = __float2bfloat16(a.y);
    u.e[2] = __float2bfloat16(a.z); u.e[3] = __float2bfloat16(a.w);
    u.e[4] = __float2bfloat16(b.x); u.e[5] = __float2bfloat16(b.y);
    u.e[6] = __float2bfloat16(b.z); u.e[7] = __float2bfloat16(b.w);
    return u.v;
}

// ---------------------------------------------------------------------------
// user rows: A0[u] = bf16(user_emb + gender_emb[g] + age_emb[a])
// ---------------------------------------------------------------------------
__global__ __launch_bounds__(256) void user_init_k(
    const float4* __restrict__ user_emb,
    const float4* __restrict__ gender_emb,
    const float4* __restrict__ age_emb,
    const int* __restrict__ ug,
    const int* __restrict__ ua,
    ushort4* __restrict__ A0)
{
    int i = blockIdx.x * 256 + threadIdx.x;   // [0, NU*16)
    int u = i >> 4, q = i & 15;
    float4 e = user_emb[i];
    float4 g = gender_emb[ug[u] * 16 + q];
    float4 a = age_emb[ua[u] * 16 + q];
    e.x += g.x + a.x; e.y += g.y + a.y; e.z += g.z + a.z; e.w += g.w + a.w;
    A0[i] = f4bf(e);
}

// ---------------------------------------------------------------------------
// W fp32 [64][384] -> bf16 in MFMA B-fragment order.
// ---------------------------------------------------------------------------
__global__ __launch_bounds__(256) void wconv_k(
    const float* __restrict__ W, short8* __restrict__ Wb)
{
    int t = blockIdx.x * 256 + threadIdx.x;   // entry index
    if (t >= 3072) return;
    int lid = t & 63, nt = (t >> 6) & 3, kt = t >> 8;
    int m16 = lid & 15, q = lid >> 4;
    const float* src = W + (size_t)(nt * 16 + m16) * BD + kt * 32 + q * 8;
    Wb[t] = cvt8(*(const float4*)src, *(const float4*)(src + 4));
}

// ---------------------------------------------------------------------------
// item rows via bf16 MFMA:
//   A0[NU+i] = bf16(item_emb[i] + cat_emb[icat[i]] + bert[i] @ W^T)
// ---------------------------------------------------------------------------
__global__ __launch_bounds__(256) void item_init_k(
    const float* __restrict__ bert,        // [NI][384]
    const short8* __restrict__ Wb,         // [3072] frag-ordered bf16 W
    const float* __restrict__ item_emb,    // [NI][64]
    const float* __restrict__ cat_emb,     // [11][64]
    const int* __restrict__ icat,
    unsigned short* __restrict__ A0)       // [NN][64] bf16
{
    const int lid = threadIdx.x & 63;
    const int wv  = threadIdx.x >> 6;
    const int i0  = (blockIdx.x * 4 + wv) * 16;
    if (i0 >= NI) return;
    const int m16 = lid & 15;
    const int q   = lid >> 4;

    const float*  ab = bert + (size_t)(i0 + m16) * BD + q * 8;
    const short8* wb = Wb + lid;

    floatx4 cf[4];
    cf[0] = (floatx4){0.f, 0.f, 0.f, 0.f};
    cf[1] = cf[0]; cf[2] = cf[0]; cf[3] = cf[0];

    // prologue: K-step 0 in flight
    float4 a0 = *(const float4*)(ab + 0);
    float4 a1 = *(const float4*)(ab + 4);
    short8 b0 = wb[0 * 64];
    short8 b1 = wb[1 * 64];
    short8 b2 = wb[2 * 64];
    short8 b3 = wb[3 * 64];

    #pragma unroll
    for (int kt = 0; kt < 11; ++kt) {
        float4 na0 = *(const float4*)(ab + (kt + 1) * 32 + 0);
        float4 na1 = *(const float4*)(ab + (kt + 1) * 32 + 4);
        short8 nb0 = wb[((kt + 1) * 4 + 0) * 64];
        short8 nb1 = wb[((kt + 1) * 4 + 1) * 64];
        short8 nb2 = wb[((kt + 1) * 4 + 2) * 64];
        short8 nb3 = wb[((kt + 1) * 4 + 3) * 64];
        short8 af = cvt8(a0, a1);
        cf[0] = __builtin_amdgcn_mfma_f32_16x16x32_bf16(af, b0, cf[0], 0, 0, 0);
        cf[1] = __builtin_amdgcn_mfma_f32_16x16x32_bf16(af, b1, cf[1], 0, 0, 0);
        cf[2] = __builtin_amdgcn_mfma_f32_16x16x32_bf16(af, b2, cf[2], 0, 0, 0);
        cf[3] = __builtin_amdgcn_mfma_f32_16x16x32_bf16(af, b3, cf[3], 0, 0, 0);
        a0 = na0; a1 = na1; b0 = nb0; b1 = nb1; b2 = nb2; b3 = nb3;
    }
    {
        short8 af = cvt8(a0, a1);
        cf[0] = __builtin_amdgcn_mfma_f32_16x16x32_bf16(af, b0, cf[0], 0, 0, 0);
        cf[1] = __builtin_amdgcn_mfma_f32_16x16x32_bf16(af, b1, cf[1], 0, 0, 0);
        cf[2] = __builtin_amdgcn_mfma_f32_16x16x32_bf16(af, b2, cf[2], 0, 0, 0);
        cf[3] = __builtin_amdgcn_mfma_f32_16x16x32_bf16(af, b3, cf[3], 0, 0, 0);
    }

    #pragma unroll
    for (int r = 0; r < 4; ++r) {
        const int item = i0 + q * 4 + r;
        const int cat  = icat[item];
        const size_t eb = (size_t)item * 64;
        const size_t abn = (size_t)(NU + item) * 64;
        #pragma unroll
        for (int td = 0; td < 4; ++td) {
            const int d = td * 16 + m16;
            A0[abn + d] = f2bfu(cf[td][r] + item_emb[eb + d] + cat_emb[cat * 64 + d]);
        }
    }
}

// ---------------------------------------------------------------------------
// CSR build: histogram -> 2-level exclusive scan -> binned 2-pass scatter
// ---------------------------------------------------------------------------
__global__ __launch_bounds__(256) void hist_k(
    const int* __restrict__ row, int* __restrict__ counts)
{
    int e = blockIdx.x * 256 + threadIdx.x;
    if (e < NE) atomicAdd(&counts[row[e]], 1);
}

__global__ __launch_bounds__(256) void scan1_k(
    const int* __restrict__ counts, int* __restrict__ offs,
    int* __restrict__ blksum)
{
    __shared__ int s[256];
    int t = threadIdx.x;
    int base = blockIdx.x * 1024 + t * 4;
    int c0 = 0, c1 = 0, c2 = 0, c3 = 0;
    if (base + 3 < NN) {
        int4 c = *(const int4*)&counts[base];
        c0 = c.x; c1 = c.y; c2 = c.z; c3 = c.w;
    } else {
        if (base + 0 < NN) c0 = counts[base + 0];
        if (base + 1 < NN) c1 = counts[base + 1];
        if (base + 2 < NN) c2 = counts[base + 2];
    }
    int tsum = c0 + c1 + c2 + c3;
    s[t] = tsum;
    __syncthreads();
    for (int d = 1; d < 256; d <<= 1) {
        int v = (t >= d) ? s[t - d] : 0;
        __syncthreads();
        s[t] += v;
        __syncthreads();
    }
    if (t == 255) blksum[blockIdx.x] = s[255];
    int e0 = s[t] - tsum, e1 = e0 + c0, e2 = e1 + c1, e3 = e2 + c2;
    if (base + 0 < NN) offs[base + 0] = e0;
    if (base + 1 < NN) offs[base + 1] = e1;
    if (base + 2 < NN) offs[base + 2] = e2;
    if (base + 3 < NN) offs[base + 3] = e3;
}

__global__ __launch_bounds__(512) void scan2_k(int* __restrict__ blksum)
{
    __shared__ int s[512];
    int t = threadIdx.x;
    int v = (t < SCAN1_BLOCKS) ? blksum[t] : 0;
    s[t] = v;
    __syncthreads();
    for (int d = 1; d < 512; d <<= 1) {
        int x = (t >= d) ? s[t - d] : 0;
        __syncthreads();
        s[t] += x;
        __syncthreads();
    }
    if (t < SCAN1_BLOCKS) blksum[t] = s[t] - v;
}

__global__ __launch_bounds__(256) void addoff_k(
    int* __restrict__ offs, const int* __restrict__ blkoff,
    int* __restrict__ cursor,
    int* __restrict__ binstart, int* __restrict__ bincur)
{
    int i = blockIdx.x * 256 + threadIdx.x;
    if (i < NN) {
        int o = offs[i] + blkoff[i >> 10];
        offs[i] = o;
        cursor[i] = o;
        if ((i & 1023) == 0) {          // bin boundary: rows [b*1024,(b+1)*1024)
            binstart[i >> 10] = o;
            bincur[i >> 10] = o;
        }
    }
}

// ---------------------------------------------------------------------------
// Pass 1: block-level counting sort of 4096-edge chunks into 1024-row bins.
// ---------------------------------------------------------------------------
__global__ __launch_bounds__(256) void binscat_k(
    const int* __restrict__ row, const int* __restrict__ col,
    const float* __restrict__ val,
    int* __restrict__ bincur,
    int2* __restrict__ tcv, int* __restrict__ trow)
{
    __shared__ int lhist[512];   // padded bin histogram / counts
    __shared__ int lexcl[512];   // local exclusive offsets
    __shared__ int lbase[512];   // global base per bin for this block
    __shared__ int s[256];
    __shared__ int2 scv[CH];     // bin-sorted (col,val)
    __shared__ int  srow[CH];    // bin-sorted row

    int t = threadIdx.x;
    int e0 = blockIdx.x * CH;
    int n = NE - e0; if (n > CH) n = CH;

    lhist[t] = 0; lhist[t + 256] = 0;
    __syncthreads();

    int r[16]; int2 cv[16]; int rk[16];
    #pragma unroll
    for (int i = 0; i < 16; ++i) {
        int idx = e0 + i * 256 + t;
        if (idx < NE) {
            r[i] = row[idx];
            cv[i].x = col[idx];
            cv[i].y = __float_as_int(val[idx]);
            rk[i] = atomicAdd(&lhist[r[i] >> 10], 1);   // rank within bin
        }
    }
    __syncthreads();

    // exclusive scan over 512 padded bins, 2 per thread
    int c0 = lhist[2 * t], c1 = lhist[2 * t + 1];
    int tsum = c0 + c1;
    s[t] = tsum;
    __syncthreads();
    for (int d = 1; d < 256; d <<= 1) {
        int v = (t >= d) ? s[t - d] : 0;
        __syncthreads();
        s[t] += v;
        __syncthreads();
    }
    int ex = s[t] - tsum;
    lexcl[2 * t] = ex; lexcl[2 * t + 1] = ex + c0;
    // one global allocation per non-empty bin
    if (2 * t < NBINS && c0 > 0)     lbase[2 * t]     = atomicAdd(&bincur[2 * t], c0);
    if (2 * t + 1 < NBINS && c1 > 0) lbase[2 * t + 1] = atomicAdd(&bincur[2 * t + 1], c1);
    __syncthreads();

    // scatter into LDS at bin-sorted positions
    #pragma unroll
    for (int i = 0; i < 16; ++i) {
        int idx = e0 + i * 256 + t;
        if (idx < NE) {
            int b = r[i] >> 10;
            int p = lexcl[b] + rk[i];
            scv[p] = cv[i];
            srow[p] = r[i];
        }
    }
    __syncthreads();

    // write out: consecutive p -> consecutive global addresses per bin run
    for (int p = t; p < n; p += 256) {
        int rr = srow[p];
        int b = rr >> 10;
        int g = lbase[b] + (p - lexcl[b]);
        tcv[g] = scv[p];
        trow[g] = rr;
    }
}

// ---------------------------------------------------------------------------
// Pass 2: one block per bin; LDS staging so the final edges write is a
// fully coalesced stream over the bin's CSR range.
// ---------------------------------------------------------------------------
__global__ __launch_bounds__(256) void scatter2_k(
    const int2* __restrict__ tcv, const int* __restrict__ trow,
    const int* __restrict__ binstart,
    int* __restrict__ cursor, int2* __restrict__ edges)
{
    __shared__ int2 scv[P2CAP];
    int b = blockIdx.x;
    int s = binstart[b];
    int e = (b + 1 < NBINS) ? binstart[b + 1] : NE;
    int cnt = e - s;

    if (cnt <= P2CAP) {
        for (int p = s + threadIdx.x; p < e; p += 256) {
            int rr = trow[p];
            int pos = atomicAdd(&cursor[rr], 1);
            scv[pos - s] = tcv[p];
        }
        __syncthreads();
        for (int p = threadIdx.x; p < cnt; p += 256)
            edges[s + p] = scv[p];
    } else {
        // safety fallback (never expected with uniform rows)
        for (int p = s + threadIdx.x; p < e; p += 256) {
            int rr = trow[p];
            int pos = atomicAdd(&cursor[rr], 1);
            edges[pos] = tcv[p];
        }
    }
}

// ---------------------------------------------------------------------------
// SpMM propagate (layers 1,2): gather bf16 x, write y = bf16(acc). No out.
// 16 lanes/row (ushort4 = 8B gather each), 16 rows/block.
// ---------------------------------------------------------------------------
__global__ __launch_bounds__(256) void spmm_bf_k(
    const ushort4* __restrict__ xb,      // bf16 gather source
    ushort4* __restrict__ yb,            // bf16 y
    const int* __restrict__ offs,
    const int* __restrict__ ends,
    const int2* __restrict__ edges)
{
    int t = threadIdx.x;
    int r = blockIdx.x * 16 + (t >> 4);
    int q = t & 15;
    int s = offs[r], e = ends[r];
    float4 acc = make_float4(0.f, 0.f, 0.f, 0.f);
    int k = s;
    for (; k + 4 <= e; k += 4) {
        int2 c0 = edges[k + 0];
        int2 c1 = edges[k + 1];
        int2 c2 = edges[k + 2];
        int2 c3 = edges[k + 3];
        ushort4 v0 = xb[c0.x * 16 + q];
        ushort4 v1 = xb[c1.x * 16 + q];
        ushort4 v2 = xb[c2.x * 16 + q];
        ushort4 v3 = xb[c3.x * 16 + q];
        fma4(acc, __int_as_float(c0.y), ub4f(v0));
        fma4(acc, __int_as_float(c1.y), ub4f(v1));
        fma4(acc, __int_as_float(c2.y), ub4f(v2));
        fma4(acc, __int_as_float(c3.y), ub4f(v3));
    }
    for (; k < e; ++k) {
        int2 cv = edges[k];
        fma4(acc, __int_as_float(cv.y), ub4f(xb[cv.x * 16 + q]));
    }
    yb[r * 16 + q] = f4bf(acc);
}

// ---------------------------------------------------------------------------
// SpMM layer 3: gather bf16 x2, then single write of the final output:
//   out[oi] = 0.25 * (x0[oi] + x1[oi] + x2[oi] + acc)     (acc = x3)
// No out read, no y write. x0/x1/x2 oi-reads are linear bf16 streams.
// ---------------------------------------------------------------------------
__global__ __launch_bounds__(256) void spmm_l3_k(
    const ushort4* __restrict__ xb,      // bf16 x2 (gather + oi)
    const ushort4* __restrict__ x0b,     // bf16 x0
    const ushort4* __restrict__ x1b,     // bf16 x1
    float4* __restrict__ out,
    const int* __restrict__ offs,
    const int* __restrict__ ends,
    const int2* __restrict__ edges)
{
    int t = threadIdx.x;
    int r = blockIdx.x * 16 + (t >> 4);
    int q = t & 15;
    int s = offs[r], e = ends[r];
    float4 acc = make_float4(0.f, 0.f, 0.f, 0.f);
    int k = s;
    for (; k + 4 <= e; k += 4) {
        int2 c0 = edges[k + 0];
        int2 c1 = edges[k + 1];
        int2 c2 = edges[k + 2];
        int2 c3 = edges[k + 3];
        ushort4 v0 = xb[c0.x * 16 + q];
        ushort4 v1 = xb[c1.x * 16 + q];
        ushort4 v2 = xb[c2.x * 16 + q];
        ushort4 v3 = xb[c3.x * 16 + q];
        fma4(acc, __int_as_float(c0.y), ub4f(v0));
        fma4(acc, __int_as_float(c1.y), ub4f(v1));
        fma4(acc, __int_as_float(c2.y), ub4f(v2));
        fma4(acc, __int_as_float(c3.y), ub4f(v3));
    }
    for (; k < e; ++k) {
        int2 cv = edges[k];
        fma4(acc, __int_as_float(cv.y), ub4f(xb[cv.x * 16 + q]));
    }
    int oi = r * 16 + q;
    float4 x0 = ub4f(x0b[oi]);
    float4 x1 = ub4f(x1b[oi]);
    float4 x2 = ub4f(xb[oi]);
    out[oi] = make_float4(0.25f * (x0.x + x1.x + x2.x + acc.x),
                          0.25f * (x0.y + x1.y + x2.y + acc.y),
                          0.25f * (x0.z + x1.z + x2.z + acc.z),
                          0.25f * (x0.w + x1.w + x2.w + acc.w));
}

// ---------------------------------------------------------------------------
extern "C" void kernel_launch(void* const* d_in, const int* in_sizes, int n_in,
                              void* d_out, int out_size, void* d_ws, size_t ws_size,
                              hipStream_t stream)
{
    const float* user_emb    = (const float*)d_in[0];
    const float* item_emb    = (const float*)d_in[1];
    const float* gender_emb  = (const float*)d_in[2];
    const float* age_emb     = (const float*)d_in[3];
    const float* cat_emb     = (const float*)d_in[4];
    const float* bert_w      = (const float*)d_in[5];
    const float* item_bert   = (const float*)d_in[6];
    const float* adj_val     = (const float*)d_in[7];
    const int*   user_gender = (const int*)d_in[8];
    const int*   user_age    = (const int*)d_in[9];
    const int*   item_cat    = (const int*)d_in[10];
    const int*   adj_row     = (const int*)d_in[11];
    const int*   adj_col     = (const int*)d_in[12];

    float* out = (float*)d_out;

    // workspace layout (all 16B aligned; region sizes unchanged from r12)
    float* A       = (float*)d_ws;                 // 76.8 MB region: A0 bf16 x0
    float* B       = A + (size_t)NN * 64;          // 76.8 MB region (overlaid)
    int2*  edges   = (int2*)(B + (size_t)NN * 64); // [NE]
    int*   offs    = (int*)(edges + NE);           // [NN] (also counts)
    int*   cursor  = offs + NN;                    // [NN]
    int*   blksum  = cursor + NN;                  // [512]
    int*   binstart= blksum + 512;                 // [512]
    int*   bincur  = binstart + 512;               // [512]
    short8* Wb     = (short8*)(bincur + 512);      // [3072] = 48 KB

    // A region: x0 in bf16 (38.4 MB used of 76.8)
    ushort4* A0_16 = (ushort4*)A;
    // B region overlays:
    //   during CSR build: tcv [NE] (12 MB) + trow [NE] (6 MB)
    //   during spmm:      B16 = bf16 x1 (38.4 MB) + A16 = bf16 x2 (38.4 MB)
    int2*    tcv  = (int2*)B;
    int*     trow = (int*)(tcv + NE);
    ushort4* B16  = (ushort4*)B;
    ushort4* A16  = B16 + (size_t)NN * 16;

    // --- CSR build ---
    hipMemsetAsync(offs, 0, (size_t)NN * sizeof(int), stream);
    hist_k<<<5860, 256, 0, stream>>>(adj_row, offs);
    scan1_k<<<SCAN1_BLOCKS, 256, 0, stream>>>(offs, offs, blksum);
    scan2_k<<<1, 512, 0, stream>>>(blksum);
    addoff_k<<<1172, 256, 0, stream>>>(offs, blksum, cursor, binstart, bincur);
    binscat_k<<<367, 256, 0, stream>>>(adj_row, adj_col, adj_val, bincur, tcv, trow);
    scatter2_k<<<NBINS, 256, 0, stream>>>(tcv, trow, binstart, cursor, edges);

    // --- layer-0 features (bf16) into A0 ---
    wconv_k<<<12, 256, 0, stream>>>(bert_w, Wb);
    user_init_k<<<12500, 256, 0, stream>>>(
        (const float4*)user_emb, (const float4*)gender_emb, (const float4*)age_emb,
        user_gender, user_age, A0_16);
    item_init_k<<<1563, 256, 0, stream>>>(
        item_bert, Wb, item_emb, cat_emb, item_cat, (unsigned short*)A0_16);

    // --- 3 propagation layers (all intermediates bf16; out written once) ---
    spmm_bf_k<<<18750, 256, 0, stream>>>(A0_16, B16, offs, cursor, edges);  // x1
    spmm_bf_k<<<18750, 256, 0, stream>>>(B16, A16, offs, cursor, edges);    // x2
    spmm_l3_k<<<18750, 256, 0, stream>>>(A16, A0_16, B16, (float4*)out,
                                         offs, cursor, edges);              // out
}

// Round 15
// 618.008 us; speedup vs baseline: 1.2631x; 1.0100x over previous
//
#include <hip/hip_runtime.h>
#include <hip/hip_bf16.h>

#define NU 200000
#define NI 100000
#define NN 300000
#define NE 1500000
#define BD 384

#define SCAN1_BLOCKS 293   // ceil(NN / 1024)
#define NBINS 293          // ceil(NN / 1024), 1024 rows per bin
#define CH 4096            // edges per binscat block (16 per thread)
#define P2CAP 6144         // pass-2 LDS staging capacity (avg bin = 5120)
#define COLMASK 0x7FFFF    // 19 bits; NN=300000 < 2^19

typedef __attribute__((ext_vector_type(8))) short short8;
typedef __attribute__((ext_vector_type(4))) float floatx4;

// ---------------------------------------------------------------------------
__device__ __forceinline__ void fma4(float4& a, float s, const float4& w) {
    a.x = fmaf(s, w.x, a.x);
    a.y = fmaf(s, w.y, a.y);
    a.z = fmaf(s, w.z, a.z);
    a.w = fmaf(s, w.w, a.w);
}

// bf16 (as ushort) -> fp32
__device__ __forceinline__ float bf2f(unsigned short v) {
    union { unsigned int u; float f; } c; c.u = ((unsigned int)v) << 16; return c.f;
}
__device__ __forceinline__ float4 ub4f(const ushort4 v) {
    return make_float4(bf2f(v.x), bf2f(v.y), bf2f(v.z), bf2f(v.w));
}
// fp32 -> bf16 bits (RNE)
__device__ __forceinline__ unsigned short f2bfu(float x) {
    union { __hip_bfloat16 b; unsigned short u; } c; c.b = __float2bfloat16(x); return c.u;
}
// fp32x4 -> bf16x4 (RNE)
__device__ __forceinline__ ushort4 f4bf(const float4 a) {
    return make_ushort4(f2bfu(a.x), f2bfu(a.y), f2bfu(a.z), f2bfu(a.w));
}

// pack 8 fp32 -> 8 bf16 (RNE)
__device__ __forceinline__ short8 cvt8(const float4 a, const float4 b) {
    union { short8 v; __hip_bfloat16 e[8]; } u;
    u.e[0] = __float2bfloat16(a.x); u.e[1] = __float2bfloat16(a.y);
    u.e[2] = __float2bfloat16(a.z); u.e[3] = __float2bfloat16(a.w);
    u.e[4] = __float2bfloat16(b.x); u.e[5] = __float2bfloat16(b.y);
    u.e[6] = __float2bfloat16(b.z); u.e[7] = __float2bfloat16(b.w);
    return u.v;
}

// ---------------------------------------------------------------------------
// user rows: A0[u] = bf16(user_emb + gender_emb[g] + age_emb[a])
// ---------------------------------------------------------------------------
__global__ __launch_bounds__(256) void user_init_k(
    const float4* __restrict__ user_emb,
    const float4* __restrict__ gender_emb,
    const float4* __restrict__ age_emb,
    const int* __restrict__ ug,
    const int* __restrict__ ua,
    ushort4* __restrict__ A0)
{
    int i = blockIdx.x * 256 + threadIdx.x;   // [0, NU*16)
    int u = i >> 4, q = i & 15;
    float4 e = user_emb[i];
    float4 g = gender_emb[ug[u] * 16 + q];
    float4 a = age_emb[ua[u] * 16 + q];
    e.x += g.x + a.x; e.y += g.y + a.y; e.z += g.z + a.z; e.w += g.w + a.w;
    A0[i] = f4bf(e);
}

// ---------------------------------------------------------------------------
// W fp32 [64][384] -> bf16 in MFMA B-fragment order.
// ---------------------------------------------------------------------------
__global__ __launch_bounds__(256) void wconv_k(
    const float* __restrict__ W, short8* __restrict__ Wb)
{
    int t = blockIdx.x * 256 + threadIdx.x;   // entry index
    if (t >= 3072) return;
    int lid = t & 63, nt = (t >> 6) & 3, kt = t >> 8;
    int m16 = lid & 15, q = lid >> 4;
    const float* src = W + (size_t)(nt * 16 + m16) * BD + kt * 32 + q * 8;
    Wb[t] = cvt8(*(const float4*)src, *(const float4*)(src + 4));
}

// ---------------------------------------------------------------------------
// item rows via bf16 MFMA, split-K x2 for latency hiding:
//   A0[NU+i] = bf16(item_emb[i] + cat_emb[icat[i]] + bert[i] @ W^T)
// Block = 4 waves = 2 pairs x (2 K-half waves). Each wave: 16 items x 64 dims
// over K-half (192 floats, 6 MFMA K-steps). kh=1 wave dumps its partials to
// LDS; kh=0 wave adds them and runs the epilogue.
// grid: NI/32 = 3125 blocks exactly (no tail).
// ---------------------------------------------------------------------------
__global__ __launch_bounds__(256) void item_init_k(
    const float* __restrict__ bert,        // [NI][384]
    const short8* __restrict__ Wb,         // [3072] frag-ordered bf16 W
    const float* __restrict__ item_emb,    // [NI][64]
    const float* __restrict__ cat_emb,     // [11][64]
    const int* __restrict__ icat,
    unsigned short* __restrict__ A0)       // [NN][64] bf16
{
    __shared__ float4 cbuf[2][4][64];      // [pair][frag][lane] = 8 KB

    const int lid  = threadIdx.x & 63;
    const int wv   = threadIdx.x >> 6;
    const int pair = wv >> 1;
    const int kh   = wv & 1;
    const int i0   = (blockIdx.x * 2 + pair) * 16;
    const int m16  = lid & 15;
    const int q    = lid >> 4;

    const float*  ab = bert + (size_t)(i0 + m16) * BD + kh * 192 + q * 8;
    const short8* wb = Wb + kh * 24 * 64 + lid;   // kh*6 K-steps * 4 frags

    floatx4 cf[4];
    cf[0] = (floatx4){0.f, 0.f, 0.f, 0.f};
    cf[1] = cf[0]; cf[2] = cf[0]; cf[3] = cf[0];

    // prologue: local K-step 0 in flight
    float4 a0 = *(const float4*)(ab + 0);
    float4 a1 = *(const float4*)(ab + 4);
    short8 b0 = wb[0 * 64];
    short8 b1 = wb[1 * 64];
    short8 b2 = wb[2 * 64];
    short8 b3 = wb[3 * 64];

    #pragma unroll
    for (int kt = 0; kt < 5; ++kt) {
        float4 na0 = *(const float4*)(ab + (kt + 1) * 32 + 0);
        float4 na1 = *(const float4*)(ab + (kt + 1) * 32 + 4);
        short8 nb0 = wb[((kt + 1) * 4 + 0) * 64];
        short8 nb1 = wb[((kt + 1) * 4 + 1) * 64];
        short8 nb2 = wb[((kt + 1) * 4 + 2) * 64];
        short8 nb3 = wb[((kt + 1) * 4 + 3) * 64];
        short8 af = cvt8(a0, a1);
        cf[0] = __builtin_amdgcn_mfma_f32_16x16x32_bf16(af, b0, cf[0], 0, 0, 0);
        cf[1] = __builtin_amdgcn_mfma_f32_16x16x32_bf16(af, b1, cf[1], 0, 0, 0);
        cf[2] = __builtin_amdgcn_mfma_f32_16x16x32_bf16(af, b2, cf[2], 0, 0, 0);
        cf[3] = __builtin_amdgcn_mfma_f32_16x16x32_bf16(af, b3, cf[3], 0, 0, 0);
        a0 = na0; a1 = na1; b0 = nb0; b1 = nb1; b2 = nb2; b3 = nb3;
    }
    {
        short8 af = cvt8(a0, a1);
        cf[0] = __builtin_amdgcn_mfma_f32_16x16x32_bf16(af, b0, cf[0], 0, 0, 0);
        cf[1] = __builtin_amdgcn_mfma_f32_16x16x32_bf16(af, b1, cf[1], 0, 0, 0);
        cf[2] = __builtin_amdgcn_mfma_f32_16x16x32_bf16(af, b2, cf[2], 0, 0, 0);
        cf[3] = __builtin_amdgcn_mfma_f32_16x16x32_bf16(af, b3, cf[3], 0, 0, 0);
    }

    // combine the two K-halves via LDS
    if (kh == 1) {
        #pragma unroll
        for (int f = 0; f < 4; ++f)
            cbuf[pair][f][lid] = make_float4(cf[f][0], cf[f][1], cf[f][2], cf[f][3]);
    }
    __syncthreads();
    if (kh == 1) return;   // after the barrier: safe

    #pragma unroll
    for (int f = 0; f < 4; ++f) {
        float4 p = cbuf[pair][f][lid];
        cf[f][0] += p.x; cf[f][1] += p.y; cf[f][2] += p.z; cf[f][3] += p.w;
    }

    #pragma unroll
    for (int r = 0; r < 4; ++r) {
        const int item = i0 + q * 4 + r;
        const int cat  = icat[item];
        const size_t eb = (size_t)item * 64;
        const size_t abn = (size_t)(NU + item) * 64;
        #pragma unroll
        for (int td = 0; td < 4; ++td) {
            const int d = td * 16 + m16;
            A0[abn + d] = f2bfu(cf[td][r] + item_emb[eb + d] + cat_emb[cat * 64 + d]);
        }
    }
}

// ---------------------------------------------------------------------------
// CSR build: histogram -> 2-level exclusive scan -> binned 2-pass scatter
// ---------------------------------------------------------------------------
__global__ __launch_bounds__(256) void hist_k(
    const int* __restrict__ row, int* __restrict__ counts)
{
    int e = blockIdx.x * 256 + threadIdx.x;
    if (e < NE) atomicAdd(&counts[row[e]], 1);
}

__global__ __launch_bounds__(256) void scan1_k(
    const int* __restrict__ counts, int* __restrict__ offs,
    int* __restrict__ blksum)
{
    __shared__ int s[256];
    int t = threadIdx.x;
    int base = blockIdx.x * 1024 + t * 4;
    int c0 = 0, c1 = 0, c2 = 0, c3 = 0;
    if (base + 3 < NN) {
        int4 c = *(const int4*)&counts[base];
        c0 = c.x; c1 = c.y; c2 = c.z; c3 = c.w;
    } else {
        if (base + 0 < NN) c0 = counts[base + 0];
        if (base + 1 < NN) c1 = counts[base + 1];
        if (base + 2 < NN) c2 = counts[base + 2];
    }
    int tsum = c0 + c1 + c2 + c3;
    s[t] = tsum;
    __syncthreads();
    for (int d = 1; d < 256; d <<= 1) {
        int v = (t >= d) ? s[t - d] : 0;
        __syncthreads();
        s[t] += v;
        __syncthreads();
    }
    if (t == 255) blksum[blockIdx.x] = s[255];
    int e0 = s[t] - tsum, e1 = e0 + c0, e2 = e1 + c1, e3 = e2 + c2;
    if (base + 0 < NN) offs[base + 0] = e0;
    if (base + 1 < NN) offs[base + 1] = e1;
    if (base + 2 < NN) offs[base + 2] = e2;
    if (base + 3 < NN) offs[base + 3] = e3;
}

__global__ __launch_bounds__(512) void scan2_k(int* __restrict__ blksum)
{
    __shared__ int s[512];
    int t = threadIdx.x;
    int v = (t < SCAN1_BLOCKS) ? blksum[t] : 0;
    s[t] = v;
    __syncthreads();
    for (int d = 1; d < 512; d <<= 1) {
        int x = (t >= d) ? s[t - d] : 0;
        __syncthreads();
        s[t] += x;
        __syncthreads();
    }
    if (t < SCAN1_BLOCKS) blksum[t] = s[t] - v;
}

__global__ __launch_bounds__(256) void addoff_k(
    int* __restrict__ offs, const int* __restrict__ blkoff,
    int* __restrict__ cursor,
    int* __restrict__ binstart, int* __restrict__ bincur)
{
    int i = blockIdx.x * 256 + threadIdx.x;
    if (i < NN) {
        int o = offs[i] + blkoff[i >> 10];
        offs[i] = o;
        cursor[i] = o;
        if ((i & 1023) == 0) {          // bin boundary: rows [b*1024,(b+1)*1024)
            binstart[i >> 10] = o;
            bincur[i >> 10] = o;
        }
    }
}

// ---------------------------------------------------------------------------
// Pass 1: block-level counting sort of 4096-edge chunks into 1024-row bins.
// tcv.x packs col (low 19 bits) | row-within-bin (bits 19..28); trow dropped.
// LDS 47 KB -> 3 blocks/CU.
// ---------------------------------------------------------------------------
__global__ __launch_bounds__(256) void binscat_k(
    const int* __restrict__ row, const int* __restrict__ col,
    const float* __restrict__ val,
    int* __restrict__ bincur,
    int2* __restrict__ tcv)
{
    __shared__ int lhist[512];          // padded bin histogram / counts
    __shared__ int lexcl[512];          // local exclusive offsets
    __shared__ int lbase[512];          // global base per bin for this block
    __shared__ int s[256];
    __shared__ int2 scv[CH];            // bin-sorted (packed col/rowlow, val)
    __shared__ unsigned short sbin[CH]; // bin id per sorted element

    int t = threadIdx.x;
    int e0 = blockIdx.x * CH;
    int n = NE - e0; if (n > CH) n = CH;

    lhist[t] = 0; lhist[t + 256] = 0;
    __syncthreads();

    int r[16]; int2 cv[16]; int rk[16];
    #pragma unroll
    for (int i = 0; i < 16; ++i) {
        int idx = e0 + i * 256 + t;
        if (idx < NE) {
            r[i] = row[idx];
            cv[i].x = col[idx] | ((r[i] & 1023) << 19);
            cv[i].y = __float_as_int(val[idx]);
            rk[i] = atomicAdd(&lhist[r[i] >> 10], 1);   // rank within bin
        }
    }
    __syncthreads();

    // exclusive scan over 512 padded bins, 2 per thread
    int c0 = lhist[2 * t], c1 = lhist[2 * t + 1];
    int tsum = c0 + c1;
    s[t] = tsum;
    __syncthreads();
    for (int d = 1; d < 256; d <<= 1) {
        int v = (t >= d) ? s[t - d] : 0;
        __syncthreads();
        s[t] += v;
        __syncthreads();
    }
    int ex = s[t] - tsum;
    lexcl[2 * t] = ex; lexcl[2 * t + 1] = ex + c0;
    // one global allocation per non-empty bin
    if (2 * t < NBINS && c0 > 0)     lbase[2 * t]     = atomicAdd(&bincur[2 * t], c0);
    if (2 * t + 1 < NBINS && c1 > 0) lbase[2 * t + 1] = atomicAdd(&bincur[2 * t + 1], c1);
    __syncthreads();

    // scatter into LDS at bin-sorted positions
    #pragma unroll
    for (int i = 0; i < 16; ++i) {
        int idx = e0 + i * 256 + t;
        if (idx < NE) {
            int b = r[i] >> 10;
            int p = lexcl[b] + rk[i];
            scv[p] = cv[i];
            sbin[p] = (unsigned short)b;
        }
    }
    __syncthreads();

    // write out: consecutive p -> consecutive global addresses per bin run
    for (int p = t; p < n; p += 256) {
        int b = sbin[p];
        int g = lbase[b] + (p - lexcl[b]);
        tcv[g] = scv[p];
    }
}

// ---------------------------------------------------------------------------
// Pass 2: one block per bin; unpack row from tcv.x high bits; LDS staging so
// the final edges write is a fully coalesced stream over the bin's CSR range.
// ---------------------------------------------------------------------------
__global__ __launch_bounds__(256) void scatter2_k(
    const int2* __restrict__ tcv,
    const int* __restrict__ binstart,
    int* __restrict__ cursor, int2* __restrict__ edges)
{
    __shared__ int2 scv[P2CAP];
    int b = blockIdx.x;
    int rbase = b << 10;
    int s = binstart[b];
    int e = (b + 1 < NBINS) ? binstart[b + 1] : NE;
    int cnt = e - s;

    if (cnt <= P2CAP) {
        for (int p = s + threadIdx.x; p < e; p += 256) {
            int2 tv = tcv[p];
            int rr = rbase + (int)(((unsigned int)tv.x) >> 19);
            int pos = atomicAdd(&cursor[rr], 1);
            scv[pos - s] = make_int2(tv.x & COLMASK, tv.y);
        }
        __syncthreads();
        for (int p = threadIdx.x; p < cnt; p += 256)
            edges[s + p] = scv[p];
    } else {
        // safety fallback (never expected with uniform rows)
        for (int p = s + threadIdx.x; p < e; p += 256) {
            int2 tv = tcv[p];
            int rr = rbase + (int)(((unsigned int)tv.x) >> 19);
            int pos = atomicAdd(&cursor[rr], 1);
            edges[pos] = make_int2(tv.x & COLMASK, tv.y);
        }
    }
}

// ---------------------------------------------------------------------------
// SpMM propagate (layers 1,2): gather bf16 x, write y = bf16(acc). No out.
// 16 lanes/row (ushort4 = 8B gather each), 16 rows/block.
// ---------------------------------------------------------------------------
__global__ __launch_bounds__(256) void spmm_bf_k(
    const ushort4* __restrict__ xb,      // bf16 gather source
    ushort4* __restrict__ yb,            // bf16 y
    const int* __restrict__ offs,
    const int* __restrict__ ends,
    const int2* __restrict__ edges)
{
    int t = threadIdx.x;
    int r = blockIdx.x * 16 + (t >> 4);
    int q = t & 15;
    int s = offs[r], e = ends[r];
    float4 acc = make_float4(0.f, 0.f, 0.f, 0.f);
    int k = s;
    for (; k + 4 <= e; k += 4) {
        int2 c0 = edges[k + 0];
        int2 c1 = edges[k + 1];
        int2 c2 = edges[k + 2];
        int2 c3 = edges[k + 3];
        ushort4 v0 = xb[c0.x * 16 + q];
        ushort4 v1 = xb[c1.x * 16 + q];
        ushort4 v2 = xb[c2.x * 16 + q];
        ushort4 v3 = xb[c3.x * 16 + q];
        fma4(acc, __int_as_float(c0.y), ub4f(v0));
        fma4(acc, __int_as_float(c1.y), ub4f(v1));
        fma4(acc, __int_as_float(c2.y), ub4f(v2));
        fma4(acc, __int_as_float(c3.y), ub4f(v3));
    }
    for (; k < e; ++k) {
        int2 cv = edges[k];
        fma4(acc, __int_as_float(cv.y), ub4f(xb[cv.x * 16 + q]));
    }
    yb[r * 16 + q] = f4bf(acc);
}

// ---------------------------------------------------------------------------
// SpMM layer 3: gather bf16 x2, then single write of the final output:
//   out[oi] = 0.25 * (x0[oi] + x1[oi] + x2[oi] + acc)     (acc = x3)
// ---------------------------------------------------------------------------
__global__ __launch_bounds__(256) void spmm_l3_k(
    const ushort4* __restrict__ xb,      // bf16 x2 (gather + oi)
    const ushort4* __restrict__ x0b,     // bf16 x0
    const ushort4* __restrict__ x1b,     // bf16 x1
    float4* __restrict__ out,
    const int* __restrict__ offs,
    const int* __restrict__ ends,
    const int2* __restrict__ edges)
{
    int t = threadIdx.x;
    int r = blockIdx.x * 16 + (t >> 4);
    int q = t & 15;
    int s = offs[r], e = ends[r];
    float4 acc = make_float4(0.f, 0.f, 0.f, 0.f);
    int k = s;
    for (; k + 4 <= e; k += 4) {
        int2 c0 = edges[k + 0];
        int2 c1 = edges[k + 1];
        int2 c2 = edges[k + 2];
        int2 c3 = edges[k + 3];
        ushort4 v0 = xb[c0.x * 16 + q];
        ushort4 v1 = xb[c1.x * 16 + q];
        ushort4 v2 = xb[c2.x * 16 + q];
        ushort4 v3 = xb[c3.x * 16 + q];
        fma4(acc, __int_as_float(c0.y), ub4f(v0));
        fma4(acc, __int_as_float(c1.y), ub4f(v1));
        fma4(acc, __int_as_float(c2.y), ub4f(v2));
        fma4(acc, __int_as_float(c3.y), ub4f(v3));
    }
    for (; k < e; ++k) {
        int2 cv = edges[k];
        fma4(acc, __int_as_float(cv.y), ub4f(xb[cv.x * 16 + q]));
    }
    int oi = r * 16 + q;
    float4 x0 = ub4f(x0b[oi]);
    float4 x1 = ub4f(x1b[oi]);
    float4 x2 = ub4f(xb[oi]);
    out[oi] = make_float4(0.25f * (x0.x + x1.x + x2.x + acc.x),
                          0.25f * (x0.y + x1.y + x2.y + acc.y),
                          0.25f * (x0.z + x1.z + x2.z + acc.z),
                          0.25f * (x0.w + x1.w + x2.w + acc.w));
}

// ---------------------------------------------------------------------------
extern "C" void kernel_launch(void* const* d_in, const int* in_sizes, int n_in,
                              void* d_out, int out_size, void* d_ws, size_t ws_size,
                              hipStream_t stream)
{
    const float* user_emb    = (const float*)d_in[0];
    const float* item_emb    = (const float*)d_in[1];
    const float* gender_emb  = (const float*)d_in[2];
    const float* age_emb     = (const float*)d_in[3];
    const float* cat_emb     = (const float*)d_in[4];
    const float* bert_w      = (const float*)d_in[5];
    const float* item_bert   = (const float*)d_in[6];
    const float* adj_val     = (const float*)d_in[7];
    const int*   user_gender = (const int*)d_in[8];
    const int*   user_age    = (const int*)d_in[9];
    const int*   item_cat    = (const int*)d_in[10];
    const int*   adj_row     = (const int*)d_in[11];
    const int*   adj_col     = (const int*)d_in[12];

    float* out = (float*)d_out;

    // workspace layout (all 16B aligned; region sizes unchanged)
    float* A       = (float*)d_ws;                 // 76.8 MB region: A0 bf16 x0
    float* B       = A + (size_t)NN * 64;          // 76.8 MB region (overlaid)
    int2*  edges   = (int2*)(B + (size_t)NN * 64); // [NE]
    int*   offs    = (int*)(edges + NE);           // [NN] (also counts)
    int*   cursor  = offs + NN;                    // [NN]
    int*   blksum  = cursor + NN;                  // [512]
    int*   binstart= blksum + 512;                 // [512]
    int*   bincur  = binstart + 512;               // [512]
    short8* Wb     = (short8*)(bincur + 512);      // [3072] = 48 KB

    // A region: x0 in bf16 (38.4 MB used of 76.8)
    ushort4* A0_16 = (ushort4*)A;
    // B region overlays:
    //   during CSR build: tcv [NE] (12 MB, packed col|rowlow)
    //   during spmm:      B16 = bf16 x1 (38.4 MB) + A16 = bf16 x2 (38.4 MB)
    int2*    tcv  = (int2*)B;
    ushort4* B16  = (ushort4*)B;
    ushort4* A16  = B16 + (size_t)NN * 16;

    // --- CSR build ---
    hipMemsetAsync(offs, 0, (size_t)NN * sizeof(int), stream);
    hist_k<<<5860, 256, 0, stream>>>(adj_row, offs);
    scan1_k<<<SCAN1_BLOCKS, 256, 0, stream>>>(offs, offs, blksum);
    scan2_k<<<1, 512, 0, stream>>>(blksum);
    addoff_k<<<1172, 256, 0, stream>>>(offs, blksum, cursor, binstart, bincur);
    binscat_k<<<367, 256, 0, stream>>>(adj_row, adj_col, adj_val, bincur, tcv);
    scatter2_k<<<NBINS, 256, 0, stream>>>(tcv, binstart, cursor, edges);

    // --- layer-0 features (bf16) into A0 ---
    wconv_k<<<12, 256, 0, stream>>>(bert_w, Wb);
    user_init_k<<<12500, 256, 0, stream>>>(
        (const float4*)user_emb, (const float4*)gender_emb, (const float4*)age_emb,
        user_gender, user_age, A0_16);
    item_init_k<<<3125, 256, 0, stream>>>(
        item_bert, Wb, item_emb, cat_emb, item_cat, (unsigned short*)A0_16);

    // --- 3 propagation layers (all intermediates bf16; out written once) ---
    spmm_bf_k<<<18750, 256, 0, stream>>>(A0_16, B16, offs, cursor, edges);  // x1
    spmm_bf_k<<<18750, 256, 0, stream>>>(B16, A16, offs, cursor, edges);    // x2
    spmm_l3_k<<<18750, 256, 0, stream>>>(A16, A0_16, B16, (float4*)out,
                                         offs, cursor, edges);              // out
}

// Round 16
// 603.044 us; speedup vs baseline: 1.2945x; 1.0248x over previous
//
#include <hip/hip_runtime.h>
#include <hip/hip_bf16.h>

#define NU 200000
#define NI 100000
#define NN 300000
#define NE 1500000
#define BD 384

#define SCAN1_BLOCKS 293   // ceil(NN / 1024)
#define NBINS 293          // ceil(NN / 1024), 1024 rows per bin
#define CH 4096            // edges per binscat block (16 per thread)
#define CAP2 8192          // fixed tmp-bin capacity (expected 5120, 42-sigma safe)
#define P2CAP 6144         // pass-2 LDS staging capacity (avg bin = 5120)
#define COLMASK 0x7FFFF    // 19 bits; NN=300000 < 2^19

typedef __attribute__((ext_vector_type(8))) short short8;
typedef __attribute__((ext_vector_type(4))) float floatx4;

// ---------------------------------------------------------------------------
__device__ __forceinline__ void fma4(float4& a, float s, const float4& w) {
    a.x = fmaf(s, w.x, a.x);
    a.y = fmaf(s, w.y, a.y);
    a.z = fmaf(s, w.z, a.z);
    a.w = fmaf(s, w.w, a.w);
}

// bf16 (as ushort) -> fp32
__device__ __forceinline__ float bf2f(unsigned short v) {
    union { unsigned int u; float f; } c; c.u = ((unsigned int)v) << 16; return c.f;
}
__device__ __forceinline__ float4 ub4f(const ushort4 v) {
    return make_float4(bf2f(v.x), bf2f(v.y), bf2f(v.z), bf2f(v.w));
}
// fp32 -> bf16 bits (RNE)
__device__ __forceinline__ unsigned short f2bfu(float x) {
    union { __hip_bfloat16 b; unsigned short u; } c; c.b = __float2bfloat16(x); return c.u;
}
// fp32x4 -> bf16x4 (RNE)
__device__ __forceinline__ ushort4 f4bf(const float4 a) {
    return make_ushort4(f2bfu(a.x), f2bfu(a.y), f2bfu(a.z), f2bfu(a.w));
}

// pack 8 fp32 -> 8 bf16 (RNE)
__device__ __forceinline__ short8 cvt8(const float4 a, const float4 b) {
    union { short8 v; __hip_bfloat16 e[8]; } u;
    u.e[0] = __float2bfloat16(a.x); u.e[1] = __float2bfloat16(a.y);
    u.e[2] = __float2bfloat16(a.z); u.e[3] = __float2bfloat16(a.w);
    u.e[4] = __float2bfloat16(b.x); u.e[5] = __float2bfloat16(b.y);
    u.e[6] = __float2bfloat16(b.z); u.e[7] = __float2bfloat16(b.w);
    return u.v;
}

// ---------------------------------------------------------------------------
// user rows: A0[u] = bf16(user_emb + gender_emb[g] + age_emb[a])
// ---------------------------------------------------------------------------
__global__ __launch_bounds__(256) void user_init_k(
    const float4* __restrict__ user_emb,
    const float4* __restrict__ gender_emb,
    const float4* __restrict__ age_emb,
    const int* __restrict__ ug,
    const int* __restrict__ ua,
    ushort4* __restrict__ A0)
{
    int i = blockIdx.x * 256 + threadIdx.x;   // [0, NU*16)
    int u = i >> 4, q = i & 15;
    float4 e = user_emb[i];
    float4 g = gender_emb[ug[u] * 16 + q];
    float4 a = age_emb[ua[u] * 16 + q];
    e.x += g.x + a.x; e.y += g.y + a.y; e.z += g.z + a.z; e.w += g.w + a.w;
    A0[i] = f4bf(e);
}

// ---------------------------------------------------------------------------
// W fp32 [64][384] -> bf16 in MFMA B-fragment order.
// ---------------------------------------------------------------------------
__global__ __launch_bounds__(256) void wconv_k(
    const float* __restrict__ W, short8* __restrict__ Wb)
{
    int t = blockIdx.x * 256 + threadIdx.x;   // entry index
    if (t >= 3072) return;
    int lid = t & 63, nt = (t >> 6) & 3, kt = t >> 8;
    int m16 = lid & 15, q = lid >> 4;
    const float* src = W + (size_t)(nt * 16 + m16) * BD + kt * 32 + q * 8;
    Wb[t] = cvt8(*(const float4*)src, *(const float4*)(src + 4));
}

// ---------------------------------------------------------------------------
// item rows via bf16 MFMA, split-K x2 for latency hiding:
//   A0[NU+i] = bf16(item_emb[i] + cat_emb[icat[i]] + bert[i] @ W^T)
// grid: NI/32 = 3125 blocks exactly (no tail).
// ---------------------------------------------------------------------------
__global__ __launch_bounds__(256) void item_init_k(
    const float* __restrict__ bert,        // [NI][384]
    const short8* __restrict__ Wb,         // [3072] frag-ordered bf16 W
    const float* __restrict__ item_emb,    // [NI][64]
    const float* __restrict__ cat_emb,     // [11][64]
    const int* __restrict__ icat,
    unsigned short* __restrict__ A0)       // [NN][64] bf16
{
    __shared__ float4 cbuf[2][4][64];      // [pair][frag][lane] = 8 KB

    const int lid  = threadIdx.x & 63;
    const int wv   = threadIdx.x >> 6;
    const int pair = wv >> 1;
    const int kh   = wv & 1;
    const int i0   = (blockIdx.x * 2 + pair) * 16;
    const int m16  = lid & 15;
    const int q    = lid >> 4;

    const float*  ab = bert + (size_t)(i0 + m16) * BD + kh * 192 + q * 8;
    const short8* wb = Wb + kh * 24 * 64 + lid;   // kh*6 K-steps * 4 frags

    floatx4 cf[4];
    cf[0] = (floatx4){0.f, 0.f, 0.f, 0.f};
    cf[1] = cf[0]; cf[2] = cf[0]; cf[3] = cf[0];

    // prologue: local K-step 0 in flight
    float4 a0 = *(const float4*)(ab + 0);
    float4 a1 = *(const float4*)(ab + 4);
    short8 b0 = wb[0 * 64];
    short8 b1 = wb[1 * 64];
    short8 b2 = wb[2 * 64];
    short8 b3 = wb[3 * 64];

    #pragma unroll
    for (int kt = 0; kt < 5; ++kt) {
        float4 na0 = *(const float4*)(ab + (kt + 1) * 32 + 0);
        float4 na1 = *(const float4*)(ab + (kt + 1) * 32 + 4);
        short8 nb0 = wb[((kt + 1) * 4 + 0) * 64];
        short8 nb1 = wb[((kt + 1) * 4 + 1) * 64];
        short8 nb2 = wb[((kt + 1) * 4 + 2) * 64];
        short8 nb3 = wb[((kt + 1) * 4 + 3) * 64];
        short8 af = cvt8(a0, a1);
        cf[0] = __builtin_amdgcn_mfma_f32_16x16x32_bf16(af, b0, cf[0], 0, 0, 0);
        cf[1] = __builtin_amdgcn_mfma_f32_16x16x32_bf16(af, b1, cf[1], 0, 0, 0);
        cf[2] = __builtin_amdgcn_mfma_f32_16x16x32_bf16(af, b2, cf[2], 0, 0, 0);
        cf[3] = __builtin_amdgcn_mfma_f32_16x16x32_bf16(af, b3, cf[3], 0, 0, 0);
        a0 = na0; a1 = na1; b0 = nb0; b1 = nb1; b2 = nb2; b3 = nb3;
    }
    {
        short8 af = cvt8(a0, a1);
        cf[0] = __builtin_amdgcn_mfma_f32_16x16x32_bf16(af, b0, cf[0], 0, 0, 0);
        cf[1] = __builtin_amdgcn_mfma_f32_16x16x32_bf16(af, b1, cf[1], 0, 0, 0);
        cf[2] = __builtin_amdgcn_mfma_f32_16x16x32_bf16(af, b2, cf[2], 0, 0, 0);
        cf[3] = __builtin_amdgcn_mfma_f32_16x16x32_bf16(af, b3, cf[3], 0, 0, 0);
    }

    // combine the two K-halves via LDS
    if (kh == 1) {
        #pragma unroll
        for (int f = 0; f < 4; ++f)
            cbuf[pair][f][lid] = make_float4(cf[f][0], cf[f][1], cf[f][2], cf[f][3]);
    }
    __syncthreads();
    if (kh == 1) return;   // after the barrier: safe

    #pragma unroll
    for (int f = 0; f < 4; ++f) {
        float4 p = cbuf[pair][f][lid];
        cf[f][0] += p.x; cf[f][1] += p.y; cf[f][2] += p.z; cf[f][3] += p.w;
    }

    #pragma unroll
    for (int r = 0; r < 4; ++r) {
        const int item = i0 + q * 4 + r;
        const int cat  = icat[item];
        const size_t eb = (size_t)item * 64;
        const size_t abn = (size_t)(NU + item) * 64;
        #pragma unroll
        for (int td = 0; td < 4; ++td) {
            const int d = td * 16 + m16;
            A0[abn + d] = f2bfu(cf[td][r] + item_emb[eb + d] + cat_emb[cat * 64 + d]);
        }
    }
}

// ---------------------------------------------------------------------------
// CSR build: fused hist+binscat (fixed-capacity bins) -> scan -> scatter2
// ---------------------------------------------------------------------------
__global__ __launch_bounds__(256) void scan1_k(
    const int* __restrict__ counts, int* __restrict__ offs,
    int* __restrict__ blksum)
{
    __shared__ int s[256];
    int t = threadIdx.x;
    int base = blockIdx.x * 1024 + t * 4;
    int c0 = 0, c1 = 0, c2 = 0, c3 = 0;
    if (base + 3 < NN) {
        int4 c = *(const int4*)&counts[base];
        c0 = c.x; c1 = c.y; c2 = c.z; c3 = c.w;
    } else {
        if (base + 0 < NN) c0 = counts[base + 0];
        if (base + 1 < NN) c1 = counts[base + 1];
        if (base + 2 < NN) c2 = counts[base + 2];
    }
    int tsum = c0 + c1 + c2 + c3;
    s[t] = tsum;
    __syncthreads();
    for (int d = 1; d < 256; d <<= 1) {
        int v = (t >= d) ? s[t - d] : 0;
        __syncthreads();
        s[t] += v;
        __syncthreads();
    }
    if (t == 255) blksum[blockIdx.x] = s[255];
    int e0 = s[t] - tsum, e1 = e0 + c0, e2 = e1 + c1, e3 = e2 + c2;
    if (base + 0 < NN) offs[base + 0] = e0;
    if (base + 1 < NN) offs[base + 1] = e1;
    if (base + 2 < NN) offs[base + 2] = e2;
    if (base + 3 < NN) offs[base + 3] = e3;
}

__global__ __launch_bounds__(512) void scan2_k(int* __restrict__ blksum)
{
    __shared__ int s[512];
    int t = threadIdx.x;
    int v = (t < SCAN1_BLOCKS) ? blksum[t] : 0;
    s[t] = v;
    __syncthreads();
    for (int d = 1; d < 512; d <<= 1) {
        int x = (t >= d) ? s[t - d] : 0;
        __syncthreads();
        s[t] += x;
        __syncthreads();
    }
    if (t < SCAN1_BLOCKS) blksum[t] = s[t] - v;
}

__global__ __launch_bounds__(256) void addoff_k(
    int* __restrict__ offs, const int* __restrict__ blkoff,
    int* __restrict__ cursor,
    int* __restrict__ binstart)
{
    int i = blockIdx.x * 256 + threadIdx.x;
    if (i < NN) {
        int o = offs[i] + blkoff[i >> 10];
        offs[i] = o;
        cursor[i] = o;
        if ((i & 1023) == 0)            // bin boundary: rows [b*1024,(b+1)*1024)
            binstart[i >> 10] = o;
    }
}

// ---------------------------------------------------------------------------
// Pass 1 (fused hist): block-level counting sort of 4096-edge chunks into
// 1024-row bins with FIXED-capacity tmp regions (bin b at b*CAP2) — no
// dependency on the scan, so the per-row histogram is fused into the edge
// load loop and hist_k is eliminated. tcv.x packs col | rowlow<<19.
// grid: ceil(NE/CH) = 367. Requires counts[] and bincur[] zeroed.
// ---------------------------------------------------------------------------
__global__ __launch_bounds__(256) void binscat_k(
    const int* __restrict__ row, const int* __restrict__ col,
    const float* __restrict__ val,
    int* __restrict__ counts,           // per-row histogram (fused)
    int* __restrict__ bincur,           // per-bin tmp allocator (zero-init)
    int2* __restrict__ tcv)             // [NBINS*CAP2]
{
    __shared__ int lhist[512];          // padded bin histogram / counts
    __shared__ int lexcl[512];          // local exclusive offsets
    __shared__ int lbase[512];          // per-bin base within tmp bin region
    __shared__ int s[256];
    __shared__ int2 scv[CH];            // bin-sorted (packed col/rowlow, val)
    __shared__ unsigned short sbin[CH]; // bin id per sorted element

    int t = threadIdx.x;
    int e0 = blockIdx.x * CH;
    int n = NE - e0; if (n > CH) n = CH;

    lhist[t] = 0; lhist[t + 256] = 0;
    __syncthreads();

    int r[16]; int2 cv[16]; int rk[16];
    #pragma unroll
    for (int i = 0; i < 16; ++i) {
        int idx = e0 + i * 256 + t;
        if (idx < NE) {
            r[i] = row[idx];
            cv[i].x = col[idx] | ((r[i] & 1023) << 19);
            cv[i].y = __float_as_int(val[idx]);
            rk[i] = atomicAdd(&lhist[r[i] >> 10], 1);   // rank within bin
            atomicAdd(&counts[r[i]], 1);                // fused row histogram
        }
    }
    __syncthreads();

    // exclusive scan over 512 padded bins, 2 per thread
    int c0 = lhist[2 * t], c1 = lhist[2 * t + 1];
    int tsum = c0 + c1;
    s[t] = tsum;
    __syncthreads();
    for (int d = 1; d < 256; d <<= 1) {
        int v = (t >= d) ? s[t - d] : 0;
        __syncthreads();
        s[t] += v;
        __syncthreads();
    }
    int ex = s[t] - tsum;
    lexcl[2 * t] = ex; lexcl[2 * t + 1] = ex + c0;
    // one tmp-region allocation per non-empty bin
    if (2 * t < NBINS && c0 > 0)     lbase[2 * t]     = atomicAdd(&bincur[2 * t], c0);
    if (2 * t + 1 < NBINS && c1 > 0) lbase[2 * t + 1] = atomicAdd(&bincur[2 * t + 1], c1);
    __syncthreads();

    // scatter into LDS at bin-sorted positions
    #pragma unroll
    for (int i = 0; i < 16; ++i) {
        int idx = e0 + i * 256 + t;
        if (idx < NE) {
            int b = r[i] >> 10;
            int p = lexcl[b] + rk[i];
            scv[p] = cv[i];
            sbin[p] = (unsigned short)b;
        }
    }
    __syncthreads();

    // write out: consecutive p -> consecutive addresses within the bin region
    for (int p = t; p < n; p += 256) {
        int b = sbin[p];
        size_t g = (size_t)b * CAP2 + lbase[b] + (p - lexcl[b]);
        tcv[g] = scv[p];
    }
}

// ---------------------------------------------------------------------------
// Pass 2: one block per bin; reads fixed-capacity tmp region; unpack row from
// tcv.x high bits; LDS staging -> fully coalesced edges write per CSR range.
// ---------------------------------------------------------------------------
__global__ __launch_bounds__(256) void scatter2_k(
    const int2* __restrict__ tcv,
    const int* __restrict__ binstart,
    int* __restrict__ cursor, int2* __restrict__ edges)
{
    __shared__ int2 scv[P2CAP];
    int b = blockIdx.x;
    int rbase = b << 10;
    int s = binstart[b];
    int e = (b + 1 < NBINS) ? binstart[b + 1] : NE;
    int cnt = e - s;
    const int2* src = tcv + (size_t)b * CAP2;

    if (cnt <= P2CAP) {
        for (int p = threadIdx.x; p < cnt; p += 256) {
            int2 tv = src[p];
            int rr = rbase + (int)(((unsigned int)tv.x) >> 19);
            int pos = atomicAdd(&cursor[rr], 1);
            scv[pos - s] = make_int2(tv.x & COLMASK, tv.y);
        }
        __syncthreads();
        for (int p = threadIdx.x; p < cnt; p += 256)
            edges[s + p] = scv[p];
    } else {
        // safety fallback (never expected with uniform rows)
        for (int p = threadIdx.x; p < cnt; p += 256) {
            int2 tv = src[p];
            int rr = rbase + (int)(((unsigned int)tv.x) >> 19);
            int pos = atomicAdd(&cursor[rr], 1);
            edges[pos] = make_int2(tv.x & COLMASK, tv.y);
        }
    }
}

// ---------------------------------------------------------------------------
// SpMM propagate (layers 1,2): gather bf16 x, write y = bf16(acc). No out.
// ---------------------------------------------------------------------------
__global__ __launch_bounds__(256) void spmm_bf_k(
    const ushort4* __restrict__ xb,      // bf16 gather source
    ushort4* __restrict__ yb,            // bf16 y
    const int* __restrict__ offs,
    const int* __restrict__ ends,
    const int2* __restrict__ edges)
{
    int t = threadIdx.x;
    int r = blockIdx.x * 16 + (t >> 4);
    int q = t & 15;
    int s = offs[r], e = ends[r];
    float4 acc = make_float4(0.f, 0.f, 0.f, 0.f);
    int k = s;
    for (; k + 4 <= e; k += 4) {
        int2 c0 = edges[k + 0];
        int2 c1 = edges[k + 1];
        int2 c2 = edges[k + 2];
        int2 c3 = edges[k + 3];
        ushort4 v0 = xb[c0.x * 16 + q];
        ushort4 v1 = xb[c1.x * 16 + q];
        ushort4 v2 = xb[c2.x * 16 + q];
        ushort4 v3 = xb[c3.x * 16 + q];
        fma4(acc, __int_as_float(c0.y), ub4f(v0));
        fma4(acc, __int_as_float(c1.y), ub4f(v1));
        fma4(acc, __int_as_float(c2.y), ub4f(v2));
        fma4(acc, __int_as_float(c3.y), ub4f(v3));
    }
    for (; k < e; ++k) {
        int2 cv = edges[k];
        fma4(acc, __int_as_float(cv.y), ub4f(xb[cv.x * 16 + q]));
    }
    yb[r * 16 + q] = f4bf(acc);
}

// ---------------------------------------------------------------------------
// SpMM layer 3: gather bf16 x2, then single write of the final output:
//   out[oi] = 0.25 * (x0[oi] + x1[oi] + x2[oi] + acc)     (acc = x3)
// ---------------------------------------------------------------------------
__global__ __launch_bounds__(256) void spmm_l3_k(
    const ushort4* __restrict__ xb,      // bf16 x2 (gather + oi)
    const ushort4* __restrict__ x0b,     // bf16 x0
    const ushort4* __restrict__ x1b,     // bf16 x1
    float4* __restrict__ out,
    const int* __restrict__ offs,
    const int* __restrict__ ends,
    const int2* __restrict__ edges)
{
    int t = threadIdx.x;
    int r = blockIdx.x * 16 + (t >> 4);
    int q = t & 15;
    int s = offs[r], e = ends[r];
    float4 acc = make_float4(0.f, 0.f, 0.f, 0.f);
    int k = s;
    for (; k + 4 <= e; k += 4) {
        int2 c0 = edges[k + 0];
        int2 c1 = edges[k + 1];
        int2 c2 = edges[k + 2];
        int2 c3 = edges[k + 3];
        ushort4 v0 = xb[c0.x * 16 + q];
        ushort4 v1 = xb[c1.x * 16 + q];
        ushort4 v2 = xb[c2.x * 16 + q];
        ushort4 v3 = xb[c3.x * 16 + q];
        fma4(acc, __int_as_float(c0.y), ub4f(v0));
        fma4(acc, __int_as_float(c1.y), ub4f(v1));
        fma4(acc, __int_as_float(c2.y), ub4f(v2));
        fma4(acc, __int_as_float(c3.y), ub4f(v3));
    }
    for (; k < e; ++k) {
        int2 cv = edges[k];
        fma4(acc, __int_as_float(cv.y), ub4f(xb[cv.x * 16 + q]));
    }
    int oi = r * 16 + q;
    float4 x0 = ub4f(x0b[oi]);
    float4 x1 = ub4f(x1b[oi]);
    float4 x2 = ub4f(xb[oi]);
    out[oi] = make_float4(0.25f * (x0.x + x1.x + x2.x + acc.x),
                          0.25f * (x0.y + x1.y + x2.y + acc.y),
                          0.25f * (x0.z + x1.z + x2.z + acc.z),
                          0.25f * (x0.w + x1.w + x2.w + acc.w));
}

// ---------------------------------------------------------------------------
extern "C" void kernel_launch(void* const* d_in, const int* in_sizes, int n_in,
                              void* d_out, int out_size, void* d_ws, size_t ws_size,
                              hipStream_t stream)
{
    const float* user_emb    = (const float*)d_in[0];
    const float* item_emb    = (const float*)d_in[1];
    const float* gender_emb  = (const float*)d_in[2];
    const float* age_emb     = (const float*)d_in[3];
    const float* cat_emb     = (const float*)d_in[4];
    const float* bert_w      = (const float*)d_in[5];
    const float* item_bert   = (const float*)d_in[6];
    const float* adj_val     = (const float*)d_in[7];
    const int*   user_gender = (const int*)d_in[8];
    const int*   user_age    = (const int*)d_in[9];
    const int*   item_cat    = (const int*)d_in[10];
    const int*   adj_row     = (const int*)d_in[11];
    const int*   adj_col     = (const int*)d_in[12];

    float* out = (float*)d_out;

    // workspace layout (all 16B aligned)
    float* A       = (float*)d_ws;                 // 76.8 MB region: A0 bf16 x0
    float* B       = A + (size_t)NN * 64;          // 76.8 MB region (overlaid)
    int2*  edges   = (int2*)(B + (size_t)NN * 64); // [NE]
    int*   offs    = (int*)(edges + NE);           // [NN] (counts -> offs)
    int*   bincur  = offs + NN;                    // [512] (adjacent: one memset)
    int*   cursor  = bincur + 512;                 // [NN]
    int*   blksum  = cursor + NN;                  // [512]
    int*   binstart= blksum + 512;                 // [512]
    short8* Wb     = (short8*)(binstart + 512);    // [3072] = 48 KB

    // A region: x0 in bf16 (38.4 MB used of 76.8)
    ushort4* A0_16 = (ushort4*)A;
    // B region overlays:
    //   during CSR build: tcv [NBINS*CAP2] (19.2 MB, fixed-stride bins)
    //   during spmm:      B16 = bf16 x1 (38.4 MB) + A16 = bf16 x2 (38.4 MB)
    int2*    tcv  = (int2*)B;
    ushort4* B16  = (ushort4*)B;
    ushort4* A16  = B16 + (size_t)NN * 16;

    // --- CSR build (hist fused into binscat; fixed-capacity tmp bins) ---
    hipMemsetAsync(offs, 0, ((size_t)NN + 512) * sizeof(int), stream); // counts+bincur
    binscat_k<<<367, 256, 0, stream>>>(adj_row, adj_col, adj_val, offs, bincur, tcv);
    scan1_k<<<SCAN1_BLOCKS, 256, 0, stream>>>(offs, offs, blksum);
    scan2_k<<<1, 512, 0, stream>>>(blksum);
    addoff_k<<<1172, 256, 0, stream>>>(offs, blksum, cursor, binstart);
    scatter2_k<<<NBINS, 256, 0, stream>>>(tcv, binstart, cursor, edges);

    // --- layer-0 features (bf16) into A0 ---
    wconv_k<<<12, 256, 0, stream>>>(bert_w, Wb);
    user_init_k<<<12500, 256, 0, stream>>>(
        (const float4*)user_emb, (const float4*)gender_emb, (const float4*)age_emb,
        user_gender, user_age, A0_16);
    item_init_k<<<3125, 256, 0, stream>>>(
        item_bert, Wb, item_emb, cat_emb, item_cat, (unsigned short*)A0_16);

    // --- 3 propagation layers (all intermediates bf16; out written once) ---
    spmm_bf_k<<<18750, 256, 0, stream>>>(A0_16, B16, offs, cursor, edges);  // x1
    spmm_bf_k<<<18750, 256, 0, stream>>>(B16, A16, offs, cursor, edges);    // x2
    spmm_l3_k<<<18750, 256, 0, stream>>>(A16, A0_16, B16, (float4*)out,
                                         offs, cursor, edges);              // out
}